// Round 13
// baseline (1009.307 us; speedup 1.0000x reference)
//
#include <hip/hip_runtime.h>
#include <hip/hip_bf16.h>

using bf = __hip_bfloat16;

#define B_   16
#define L_   12
#define N_   358
#define D_   152
#define TOK_ (B_*L_*N_)   /* 68736 */
#define FF_  256
#define HD_  38
#define SCALE_ 0.16222142113076254f  /* 38^-0.5 */
#define C2_   0.23403921469340696f   /* SCALE_ * log2(e) */

__device__ __forceinline__ float bf2f(bf x) { return __bfloat162float(x); }
__device__ __forceinline__ bf f2bf(float f) { return __float2bfloat16(f); }
__device__ __forceinline__ float lo_bf(unsigned u) { return __uint_as_float(u << 16); }
__device__ __forceinline__ float hi_bf(unsigned u) { return __uint_as_float(u & 0xffff0000u); }
__device__ __forceinline__ unsigned pk_bf(float a, float b) {
  union { bf h; unsigned short u; } A, Bu;
  A.h = f2bf(a); Bu.h = f2bf(b);
  return ((unsigned)Bu.u << 16) | A.u;
}
__device__ __forceinline__ ushort f2bf_u(float f) {
  union { bf h; ushort u; } t; t.h = f2bf(f); return t.u;
}

using short8  = __attribute__((ext_vector_type(8))) short;
using float4v = __attribute__((ext_vector_type(4))) float;

/* async global->LDS, 16B per lane; dst is wave-uniform base (HW adds lane*16) */
__device__ __forceinline__ void gl_lds16(const void* g, void* l) {
  __builtin_amdgcn_global_load_lds(
      (const __attribute__((address_space(1))) void*)g,
      (__attribute__((address_space(3))) void*)l, 16, 0, 0);
}

/* copy SUBCB bytes global->LDS; 8 waves interleave 1024B blocks */
template<int SUBCB>
__device__ __forceinline__ void issue_w8(const char* gsrc, ushort* lds, int w, int lane) {
  constexpr int TB = SUBCB >> 10;
  constexpr int TAIL = SUBCB & 1023;
#pragma unroll
  for (int blk0 = 0; blk0 < TB; blk0 += 8) {
    int blk = blk0 + w;
    if (blk < TB)
      gl_lds16(gsrc + blk*1024 + (size_t)lane*16, (char*)lds + blk*1024);
  }
  if (TAIL) {
    if (w == (TB & 7) && lane < TAIL/16)
      gl_lds16(gsrc + TB*1024 + (size_t)lane*16, (char*)lds + TB*1024);
  }
}

/* per-wave count of gl_lds16 issues done by issue_w8<SUBCB> (wave-uniform) */
template<int SUBCB>
__device__ __forceinline__ int issue_cnt(int w) {
  constexpr int TB = SUBCB >> 10;
  constexpr int TAIL = SUBCB & 1023;
  int n = (TB > 8 && w < TB - 8) ? 2 : 1;
  if (TAIL && w == (TB & 7)) n += 1;
  return n;
}

/* counted-vmcnt wait: keep newest n loads in flight (n in {1,2,3}) */
__device__ __forceinline__ void vm_wait(int n) {
  if (n == 1)      asm volatile("s_waitcnt vmcnt(1)" ::: "memory");
  else if (n == 2) asm volatile("s_waitcnt vmcnt(2)" ::: "memory");
  else             asm volatile("s_waitcnt vmcnt(3)" ::: "memory");
}

/* 16B logical load from a 4B-aligned (not necessarily 16B-aligned) address */
__device__ __forceinline__ short8 ld_g8(const ushort* p) {
  union { unsigned u[4]; short8 v; } t;
  t.u[0] = *(const unsigned*)(p);
  t.u[1] = *(const unsigned*)(p + 2);
  t.u[2] = *(const unsigned*)(p + 4);
  t.u[3] = *(const unsigned*)(p + 6);
  return t.v;
}

/* ------------------------------------------------------------------ */
__global__ void k_beacon(float* out, int n, float val) {
  int i = blockIdx.x * 256 + threadIdx.x;
  if (i < n) out[i] = val;
}

/* ================= fused prep: wprep | embed | evt1 | wcomb ======= */
#define WPREP_B 2700
#define EMB_B   269
#define EVT_B   128
#define WC_B    86
#define PREP_B  (WPREP_B + EMB_B + EVT_B + WC_B)   /* 3183 */

__device__ void d_wprep(int bid, int tid,
    const float* __restrict__ Wq, const float* __restrict__ Wk,
    const float* __restrict__ Wv, const float* __restrict__ Wo,
    const float* __restrict__ W1, const float* __restrict__ W2,
    unsigned* __restrict__ out) {
  int i = bid * 256 + tid;
  if (i >= 6*115200) return;
  int layer = i / 115200, r = i % 115200;
  const float* src; int K, Nd, d, up, c;
  if (r < 48000) {
    c = r / 9600; int rr = r % 9600; int m = rr / 3200; int r2 = rr % 3200;
    d = r2 / 20; up = r2 % 20;
    src = (m == 0 ? Wq : (m == 1 ? Wk : Wv)) + layer*23104; K = 152; Nd = 152;
  } else if (r < 64000) {
    int rr = r - 48000; c = rr / 3200; int r2 = rr % 3200;
    d = r2 / 20; up = r2 % 20;
    src = Wo + layer*23104; K = 152; Nd = 152;
  } else if (r < 89600) {
    int rr = r - 64000; c = rr / 5120; int r2 = rr % 5120;
    d = r2 / 20; up = r2 % 20;
    src = W1 + layer*38912; K = 152; Nd = 256;
  } else {
    int rr = r - 89600; c = rr / 3200; int r2 = rr % 3200;
    d = r2 / 20; up = r2 % 20;
    src = W2 + layer*38912; K = 256; Nd = 152;
  }
  float v0 = 0.f, v1 = 0.f;
  int k0 = 32*c + 2*up;
  if (up < 16 && d < Nd) {
    if (k0 < K)     v0 = src[(long)k0*Nd + d];
    if (k0 + 1 < K) v1 = src[(long)(k0+1)*Nd + d];
  }
  out[i] = pk_bf(v0, v1);
}

__device__ void d_embed(int bid, int tid,
    const float* __restrict__ var_x, const float* __restrict__ marker,
    const float* __restrict__ W_in, const float* __restrict__ b_in,
    const float* __restrict__ tod_emb, const float* __restrict__ dow_emb,
    const float* __restrict__ adap, bf* __restrict__ x) {
  int t = bid * 256 + tid;
  if (t >= TOK_) return;
  int n = t % N_;
  int l = (t / N_) % L_;
  float var = var_x[t];
  float m0 = marker[t*4 + 0];
  float m1 = marker[t*4 + 1];
  int tod = (int)(m0 * 144.f); tod = tod < 0 ? 0 : (tod > 143 ? 143 : tod);
  int dw  = (int)(m1 * 7.f);   dw  = dw  < 0 ? 0 : (dw  > 6   ? 6   : dw);
  bf* xp = x + (long)t * D_;
  for (int d = 0; d < 24; ++d)
    xp[d] = f2bf(var * W_in[d] + m0 * W_in[24 + d] + m1 * W_in[48 + d] + b_in[d]);
  for (int d = 0; d < 24; ++d) xp[24 + d] = f2bf(tod_emb[tod*24 + d]);
  for (int d = 0; d < 24; ++d) xp[48 + d] = f2bf(dow_emb[dw*24 + d]);
  for (int d = 0; d < 80; ++d) xp[72 + d] = f2bf(adap[(l*N_ + n)*80 + d]);
}

__device__ void d_evt1(int bk, int tid,
    const float* __restrict__ marker, const int* __restrict__ doy_idx,
    const float* __restrict__ emb, const float* __restrict__ W_evt,
    const float* __restrict__ b_evt, float* __restrict__ evt_h) {
  int b = bk >> 3; int ks = bk & 7;
  float m3 = marker[((b*L_ + (L_-1))*N_ + 0)*4 + 3];
  int doy = (int)(m3 * 365.f); doy = doy < 0 ? 0 : (doy > 365 ? 365 : doy);
  int idx = doy_idx[doy*8 + ks];
  if (idx < 0 || idx > 4096) idx = 0;
  int d = tid;
  float acc = b_evt[d];
  const float* er = emb + (long)idx * 1024;
  for (int e = 0; e < 1024; ++e)
    acc += er[e] * W_evt[e*256 + d];
  evt_h[bk*256 + d] = acc;
}

__device__ void d_wcomb(int bid, int tid,
    const float* __restrict__ W_mm, const float* __restrict__ W_ts,
    float* __restrict__ wcomb, float* __restrict__ wevtsum) {
  int i = bid * 256 + tid;
  if (i < 1824*12) {
    int r = i / 12, p = i % 12, l = r / 152, d = r % 152;
    wcomb[i] = W_mm[(l*408 + 256 + d)*12 + p] + W_ts[i];
  }
  if (i < 256*12) {
    int e = i / 12, p = i % 12;
    float s = 0.f;
    for (int l = 0; l < 12; ++l) s += W_mm[(l*408 + e)*12 + p];
    wevtsum[i] = s;
  }
}

__global__ __launch_bounds__(256) void k_prep(
    const float* Wq, const float* Wk, const float* Wv, const float* Wo,
    const float* W1, const float* W2, unsigned* wout,
    const float* var_x, const float* marker, const float* W_in,
    const float* b_in, const float* tod_emb, const float* dow_emb,
    const float* adap, bf* x,
    const int* doyi, const float* emb, const float* W_evt,
    const float* b_evt, float* evt_h,
    const float* W_mm, const float* W_ts, float* wcomb, float* wevtsum) {
  int bid = blockIdx.x, tid = threadIdx.x;
  if (bid < WPREP_B)
    d_wprep(bid, tid, Wq, Wk, Wv, Wo, W1, W2, wout);
  else if (bid < WPREP_B + EMB_B)
    d_embed(bid - WPREP_B, tid, var_x, marker, W_in, b_in, tod_emb, dow_emb, adap, x);
  else if (bid < WPREP_B + EMB_B + EVT_B)
    d_evt1(bid - WPREP_B - EMB_B, tid, marker, doyi, emb, W_evt, b_evt, evt_h);
  else
    d_wcomb(bid - WPREP_B - EMB_B - EVT_B, tid, W_mm, W_ts, wcomb, wevtsum);
}

/* ------------------------------------------------------------------ */
/* GEMM v8 (round-7/9 proven): counted-vmcnt two-barrier K-loop.
   Used only for the fused QKV projection.                            */
template<int K, int Nd, int NW, int TOKB, int CSPLIT, bool RELU, bool LN>
__global__ __launch_bounds__(512) void k_gemm7(
    const bf* __restrict__ X, const ushort* __restrict__ Wg,
    const float* __restrict__ bi0, const float* __restrict__ bi1,
    const float* __restrict__ bi2, const bf* __restrict__ Res,
    const float* __restrict__ g, const float* __restrict__ bb,
    bf* __restrict__ Y0, bf* __restrict__ Y1, bf* __restrict__ Y2) {
  constexpr int NJ   = (Nd + 15) / 16;
  constexpr int NdP  = NJ * 16;
  constexpr int KC   = (K + 31) / 32;
  constexpr int G    = NW * CSPLIT;
  constexpr int S    = KC * G;
  constexpr int IR   = NdP / CSPLIT;
  constexpr int SUB_USH = IR * 40;
  constexpr int SUBCB   = SUB_USH * 2;
  constexpr int NJW  = IR / 32;
  constexpr int MR   = TOKB / 64;
  constexpr bool GLX = (K == 152);
  constexpr int XSTR = GLX ? K : (K + 8);
  __shared__ __align__(16) ushort Xs[TOKB * XSTR + 8];
  __shared__ __align__(16) ushort Wb[2 * SUB_USH];
  long row0 = (long)blockIdx.x * TOKB;
  int tid = threadIdx.x;
  int lane = tid & 63, w = tid >> 6;
  int cl = lane & 15, gr = lane >> 4;
  int wr = w >> 1, wc = w & 1;
  if constexpr (GLX) {
    constexpr int TBX = TOKB * K * 2 / 1024;
    const char* Xgc = (const char*)(X + row0 * K);
#pragma unroll
    for (int b0 = 0; b0 < TBX; b0 += 8) {
      int blk = b0 + w;
      if (blk < TBX)
        gl_lds16(Xgc + blk*1024 + (size_t)lane*16, (char*)Xs + blk*1024);
    }
  } else {
    const char* Xgc = (const char*)(X + row0 * K);
    for (int i = tid; i < TOKB*(K/8); i += 512) {
      int r = i / (K/8), c = i % (K/8);
      *(short8*)&Xs[r*XSTR + 8*c] = *(const short8*)(Xgc + r*(K*2) + c*16);
    }
    __syncthreads();
  }
  const char* gW = (const char*)Wg;
  issue_w8<SUBCB>(gW, Wb, w, lane);
  const int nw = issue_cnt<SUBCB>(w);
  float4v acc[G][MR][NJW];
#pragma unroll
  for (int gi = 0; gi < G; ++gi)
#pragma unroll
    for (int mi = 0; mi < MR; ++mi)
#pragma unroll
      for (int j = 0; j < NJW; ++j) acc[gi][mi][j] = (float4v){0.f,0.f,0.f,0.f};
#pragma unroll
  for (int s = 0; s < S; ++s) {
    if (s + 1 < S) {
      issue_w8<SUBCB>(gW + (size_t)(s+1)*SUBCB, Wb + ((s+1)&1)*SUB_USH, w, lane);
      vm_wait(nw);
    } else {
      asm volatile("s_waitcnt vmcnt(0)" ::: "memory");
    }
    __builtin_amdgcn_s_barrier();
    int kc = (s / G) * 32;
    const ushort* wb = Wb + (s&1)*SUB_USH;
    short8 af[MR];
#pragma unroll
    for (int mi = 0; mi < MR; ++mi)
      af[mi] = *(const short8*)&Xs[((TOKB/4)*wr + 16*mi + cl)*XSTR + kc + 8*gr];
#pragma unroll
    for (int j = 0; j < NJW; ++j) {
      short8 bv = *(const short8*)&wb[((IR/2)*wc + 16*j + cl)*40 + 8*gr];
#pragma unroll
      for (int mi = 0; mi < MR; ++mi)
        acc[s % G][mi][j] =
            __builtin_amdgcn_mfma_f32_16x16x32_bf16(af[mi], bv, acc[s % G][mi][j], 0, 0, 0);
    }
    asm volatile("s_waitcnt lgkmcnt(0)" ::: "memory");
    __builtin_amdgcn_s_barrier();
  }
  if constexpr (!LN) {
#pragma unroll
    for (int gi = 0; gi < G; ++gi) {
      bf* Y = (NW > 1) ? (gi == 0 ? Y0 : (gi == 1 ? Y1 : Y2)) : Y0;
      const float* bp = (NW > 1) ? (gi == 0 ? bi0 : (gi == 1 ? bi1 : bi2)) : bi0;
      int colb = (CSPLIT > 1 ? IR*gi : 0) + (IR/2)*wc;
#pragma unroll
      for (int j = 0; j < NJW; ++j) {
        int col = colb + 16*j + cl;
        if (col < Nd) {
          float bvs = bp[col];
#pragma unroll
          for (int mi = 0; mi < MR; ++mi) {
            long rw = row0 + (TOKB/4)*wr + 16*mi + 4*gr;
#pragma unroll
            for (int r = 0; r < 4; ++r) {
              float val = acc[gi][mi][j][r] + bvs;
              if (RELU) val = fmaxf(val, 0.f);
              Y[(rw + r) * Nd + col] = f2bf(val);
            }
          }
        }
      }
    }
  } else {
    float* LNb = (float*)Wb;
    int colb = (IR/2)*wc;
#pragma unroll
    for (int j = 0; j < NJW; ++j) {
      int col = colb + 16*j + cl;
      if (col < Nd) {
        float bvs = bi0[col];
#pragma unroll
        for (int mi = 0; mi < MR; ++mi) {
          long rw = row0 + (TOKB/4)*wr + 16*mi + 4*gr;
#pragma unroll
          for (int r = 0; r < 4; ++r)
            acc[0][mi][j][r] += bvs + bf2f(Res[(rw + r) * Nd + col]);
        }
      }
    }
    float mean[MR][4], rs[MR][4];
#pragma unroll
    for (int mi = 0; mi < MR; ++mi)
#pragma unroll
      for (int r = 0; r < 4; ++r) {
        float s = 0.f;
#pragma unroll
        for (int j = 0; j < NJW; ++j) s += acc[0][mi][j][r];
        s += __shfl_xor(s, 1, 64); s += __shfl_xor(s, 2, 64);
        s += __shfl_xor(s, 4, 64); s += __shfl_xor(s, 8, 64);
        if (cl == 0) LNb[((wr*MR + mi)*2 + wc)*16 + 4*gr + r] = s;
      }
    __syncthreads();
#pragma unroll
    for (int mi = 0; mi < MR; ++mi)
#pragma unroll
      for (int r = 0; r < 4; ++r) {
        float tot = LNb[((wr*MR + mi)*2 + 0)*16 + 4*gr + r]
                  + LNb[((wr*MR + mi)*2 + 1)*16 + 4*gr + r];
        mean[mi][r] = tot * (1.f / (float)Nd);
      }
#pragma unroll
    for (int mi = 0; mi < MR; ++mi)
#pragma unroll
      for (int r = 0; r < 4; ++r) {
        float s2 = 0.f;
#pragma unroll
        for (int j = 0; j < NJW; ++j) {
          int col = colb + 16*j + cl;
          if (col < Nd) {
            float dv = acc[0][mi][j][r] - mean[mi][r];
            s2 += dv*dv;
          }
        }
        s2 += __shfl_xor(s2, 1, 64); s2 += __shfl_xor(s2, 2, 64);
        s2 += __shfl_xor(s2, 4, 64); s2 += __shfl_xor(s2, 8, 64);
        if (cl == 0) LNb[256 + ((wr*MR + mi)*2 + wc)*16 + 4*gr + r] = s2;
      }
    __syncthreads();
#pragma unroll
    for (int mi = 0; mi < MR; ++mi)
#pragma unroll
      for (int r = 0; r < 4; ++r) {
        float tot2 = LNb[256 + ((wr*MR + mi)*2 + 0)*16 + 4*gr + r]
                   + LNb[256 + ((wr*MR + mi)*2 + 1)*16 + 4*gr + r];
        rs[mi][r] = rsqrtf(tot2 * (1.f / (float)Nd) + 1e-5f);
      }
#pragma unroll
    for (int j = 0; j < NJW; ++j) {
      int col = colb + 16*j + cl;
      if (col < Nd) {
        float gv = g[col], bv2 = bb[col];
#pragma unroll
        for (int mi = 0; mi < MR; ++mi) {
          long rw = row0 + (TOKB/4)*wr + 16*mi + 4*gr;
#pragma unroll
          for (int r = 0; r < 4; ++r)
            Y0[(rw + r) * Nd + col] =
                f2bf((acc[0][mi][j][r] - mean[mi][r]) * rs[mi][r] * gv + bv2);
        }
      }
    }
  }
}

/* ------------------------------------------------------------------ */
/* k_layer3 (round-11 proven): fused Wo+LN1+FF1+ReLU+FF2+LN2.
   ALL sync = __syncthreads() (full per-wave vmcnt+lgkmcnt drain).    */
__global__ __launch_bounds__(512) void k_layer3(
    const bf* __restrict__ A, const bf* __restrict__ Xres,
    const ushort* __restrict__ Wog, const ushort* __restrict__ W1g,
    const ushort* __restrict__ W2g,
    const float* __restrict__ bo, const float* __restrict__ b1,
    const float* __restrict__ b2,
    const float* __restrict__ g1v, const float* __restrict__ be1,
    const float* __restrict__ g2v, const float* __restrict__ be2,
    bf* __restrict__ Y) {
  constexpr int S0 = 5,  SUB0 = 6400;
  constexpr int S1 = 10, SUB1 = 5120;
  constexpr int S2 = 8,  SUB2 = 6400;
  constexpr int HSTR = 260;
  __shared__ __align__(16) ushort S_[29440];
  ushort* Xs  = S_;
  ushort* W0b = S_ + 9728;
  ushort* W1b = S_ + 9728;
  ushort* Hs2 = S_;
  ushort* W2b = S_ + 16640;
  float*  LNb1 = (float*)(S_ + 22528);
  long row0 = (long)blockIdx.x * 64;
  int tid = threadIdx.x, lane = tid & 63, w = tid >> 6;
  int cl = lane & 15, gr = lane >> 4;
  int wr = w >> 1, wc = w & 1;
  int colb = 80*wc;
  {
    const char* Agc = (const char*)(A + row0 * 152);
#pragma unroll
    for (int b0 = 0; b0 < 19; b0 += 8) {
      int blk = b0 + w;
      if (blk < 19)
        gl_lds16(Agc + blk*1024 + (size_t)lane*16, (char*)Xs + blk*1024);
    }
  }
  issue_w8<SUB0*2>((const char*)Wog, W0b, w, lane);
  __syncthreads();
  float4v acc0[5];
#pragma unroll
  for (int j = 0; j < 5; ++j) acc0[j] = (float4v){0.f,0.f,0.f,0.f};
#pragma unroll
  for (int s = 0; s < S0; ++s) {
    if (s + 1 < S0)
      issue_w8<SUB0*2>((const char*)Wog + (size_t)(s+1)*SUB0*2,
                       W0b + ((s+1)&1)*SUB0, w, lane);
    int kc = s * 32;
    const ushort* wb = W0b + (s&1)*SUB0;
    short8 af = *(const short8*)&Xs[(16*wr + cl)*152 + kc + 8*gr];
#pragma unroll
    for (int j = 0; j < 5; ++j) {
      short8 bv = *(const short8*)&wb[(80*wc + 16*j + cl)*40 + 8*gr];
      acc0[j] =
          __builtin_amdgcn_mfma_f32_16x16x32_bf16(af, bv, acc0[j], 0, 0, 0);
    }
    __syncthreads();
  }
#pragma unroll
  for (int j = 0; j < 5; ++j) {
    int col = colb + 16*j + cl;
    if (col < D_) {
      float bvs = bo[col];
#pragma unroll
      for (int r = 0; r < 4; ++r)
        acc0[j][r] += bvs + bf2f(Xres[(row0 + 16*wr + 4*gr + r) * D_ + col]);
    }
  }
  float mean1[4], rsv1[4];
#pragma unroll
  for (int r = 0; r < 4; ++r) {
    float s = 0.f;
#pragma unroll
    for (int j = 0; j < 5; ++j)
      if (colb + 16*j + cl < D_) s += acc0[j][r];
    s += __shfl_xor(s, 1, 64); s += __shfl_xor(s, 2, 64);
    s += __shfl_xor(s, 4, 64); s += __shfl_xor(s, 8, 64);
    if (cl == 0) LNb1[(wr*2 + wc)*16 + 4*gr + r] = s;
  }
  __syncthreads();
#pragma unroll
  for (int r = 0; r < 4; ++r) {
    float tot = LNb1[(wr*2 + 0)*16 + 4*gr + r] + LNb1[(wr*2 + 1)*16 + 4*gr + r];
    mean1[r] = tot * (1.f / (float)D_);
  }
#pragma unroll
  for (int r = 0; r < 4; ++r) {
    float s2 = 0.f;
#pragma unroll
    for (int j = 0; j < 5; ++j) {
      int col = colb + 16*j + cl;
      if (col < D_) { float dv = acc0[j][r] - mean1[r]; s2 += dv*dv; }
    }
    s2 += __shfl_xor(s2, 1, 64); s2 += __shfl_xor(s2, 2, 64);
    s2 += __shfl_xor(s2, 4, 64); s2 += __shfl_xor(s2, 8, 64);
    if (cl == 0) LNb1[128 + (wr*2 + wc)*16 + 4*gr + r] = s2;
  }
  __syncthreads();
#pragma unroll
  for (int r = 0; r < 4; ++r) {
    float tot2 = LNb1[128 + (wr*2 + 0)*16 + 4*gr + r]
               + LNb1[128 + (wr*2 + 1)*16 + 4*gr + r];
    rsv1[r] = rsqrtf(tot2 * (1.f / (float)D_) + 1e-5f);
  }
  unsigned hres[5][2];
#pragma unroll
  for (int j = 0; j < 5; ++j) {
    int col = colb + 16*j + cl;
    if (col < D_) {
      float gv = g1v[col], bv2 = be1[col];
      ushort u[4];
#pragma unroll
      for (int r = 0; r < 4; ++r) {
        u[r] = f2bf_u((acc0[j][r] - mean1[r]) * rsv1[r] * gv + bv2);
        Xs[(16*wr + 4*gr + r)*152 + col] = u[r];
      }
      hres[j][0] = (unsigned)u[0] | ((unsigned)u[1] << 16);
      hres[j][1] = (unsigned)u[2] | ((unsigned)u[3] << 16);
    } else {
      hres[j][0] = 0u; hres[j][1] = 0u;
    }
  }
  issue_w8<SUB1*2>((const char*)W1g, W1b, w, lane);
  __syncthreads();
  float4v acc1[2][4];
#pragma unroll
  for (int g2 = 0; g2 < 2; ++g2)
#pragma unroll
    for (int j = 0; j < 4; ++j) acc1[g2][j] = (float4v){0.f,0.f,0.f,0.f};
#pragma unroll
  for (int s = 0; s < S1; ++s) {
    if (s + 1 < S1)
      issue_w8<SUB1*2>((const char*)W1g + (size_t)(s+1)*SUB1*2,
                       W1b + ((s+1)&1)*SUB1, w, lane);
    int kc = (s / 2) * 32;
    const ushort* wb = W1b + (s&1)*SUB1;
    short8 af = *(const short8*)&Xs[(16*wr + cl)*152 + kc + 8*gr];
#pragma unroll
    for (int j = 0; j < 4; ++j) {
      short8 bv = *(const short8*)&wb[(64*wc + 16*j + cl)*40 + 8*gr];
      acc1[s&1][j] =
          __builtin_amdgcn_mfma_f32_16x16x32_bf16(af, bv, acc1[s&1][j], 0, 0, 0);
    }
    __syncthreads();
  }
#pragma unroll
  for (int g2 = 0; g2 < 2; ++g2)
#pragma unroll
    for (int j = 0; j < 4; ++j) {
      int col = g2*128 + 64*wc + 16*j + cl;
      float bvs = b1[col];
#pragma unroll
      for (int r = 0; r < 4; ++r) {
        int row = 16*wr + 4*gr + r;
        Hs2[row*HSTR + col] = f2bf_u(fmaxf(acc1[g2][j][r] + bvs, 0.f));
      }
    }
  issue_w8<SUB2*2>((const char*)W2g, W2b, w, lane);
  __syncthreads();
  float4v acc2[5];
#pragma unroll
  for (int j = 0; j < 5; ++j) acc2[j] = (float4v){0.f,0.f,0.f,0.f};
#pragma unroll
  for (int s = 0; s < S2; ++s) {
    if (s + 1 < S2)
      issue_w8<SUB2*2>((const char*)W2g + (size_t)(s+1)*SUB2*2,
                       W2b + ((s+1)&1)*SUB2, w, lane);
    int kc = s * 32;
    const ushort* wb = W2b + (s&1)*SUB2;
    short8 af = *(const short8*)&Hs2[(16*wr + cl)*HSTR + kc + 8*gr];
#pragma unroll
    for (int j = 0; j < 5; ++j) {
      short8 bv = *(const short8*)&wb[(80*wc + 16*j + cl)*40 + 8*gr];
      acc2[j] =
          __builtin_amdgcn_mfma_f32_16x16x32_bf16(af, bv, acc2[j], 0, 0, 0);
    }
    __syncthreads();
  }
  float* LNb = (float*)W2b;
#pragma unroll
  for (int j = 0; j < 5; ++j) {
    int col = colb + 16*j + cl;
    if (col < D_) {
      float bvs = b2[col];
#pragma unroll
      for (int r = 0; r < 4; ++r)
        acc2[j][r] += bvs + ((r & 1) ? hi_bf(hres[j][r>>1]) : lo_bf(hres[j][r>>1]));
    }
  }
  float mean[4], rsv[4];
#pragma unroll
  for (int r = 0; r < 4; ++r) {
    float s = 0.f;
#pragma unroll
    for (int j = 0; j < 5; ++j)
      if (colb + 16*j + cl < D_) s += acc2[j][r];
    s += __shfl_xor(s, 1, 64); s += __shfl_xor(s, 2, 64);
    s += __shfl_xor(s, 4, 64); s += __shfl_xor(s, 8, 64);
    if (cl == 0) LNb[(wr*2 + wc)*16 + 4*gr + r] = s;
  }
  __syncthreads();
#pragma unroll
  for (int r = 0; r < 4; ++r) {
    float tot = LNb[(wr*2 + 0)*16 + 4*gr + r] + LNb[(wr*2 + 1)*16 + 4*gr + r];
    mean[r] = tot * (1.f / (float)D_);
  }
#pragma unroll
  for (int r = 0; r < 4; ++r) {
    float s2 = 0.f;
#pragma unroll
    for (int j = 0; j < 5; ++j) {
      int col = colb + 16*j + cl;
      if (col < D_) { float dv = acc2[j][r] - mean[r]; s2 += dv*dv; }
    }
    s2 += __shfl_xor(s2, 1, 64); s2 += __shfl_xor(s2, 2, 64);
    s2 += __shfl_xor(s2, 4, 64); s2 += __shfl_xor(s2, 8, 64);
    if (cl == 0) LNb[128 + (wr*2 + wc)*16 + 4*gr + r] = s2;
  }
  __syncthreads();
#pragma unroll
  for (int r = 0; r < 4; ++r) {
    float tot2 = LNb[128 + (wr*2 + 0)*16 + 4*gr + r]
               + LNb[128 + (wr*2 + 1)*16 + 4*gr + r];
    rsv[r] = rsqrtf(tot2 * (1.f / (float)D_) + 1e-5f);
  }
#pragma unroll
  for (int j = 0; j < 5; ++j) {
    int col = colb + 16*j + cl;
    if (col < D_) {
      float gv = g2v[col], bv2 = be2[col];
#pragma unroll
      for (int r = 0; r < 4; ++r)
        Y[(row0 + 16*wr + 4*gr + r) * D_ + col] =
            f2bf((acc2[j][r] - mean[r]) * rsv[r] * gv + bv2);
    }
  }
}

/* ------------------------------------------------------------------ */
/* Temporal attention v2 (round-5 proven): MFMA swapped-operand.      */
__global__ __launch_bounds__(256) void k_attn_t2(
    const ushort* __restrict__ qg, const ushort* __restrict__ kg,
    const ushort* __restrict__ vg, bf* __restrict__ a) {
  int id = blockIdx.x; int b = id / N_; int n = id % N_;
  __shared__ ushort Ksh[4][16][40];
  __shared__ ushort Qsh[4][16][40];
  __shared__ ushort Vth[4][40][16];
  int tid = threadIdx.x;
  for (int i = tid; i < 1280; i += 256) {
    ((unsigned*)Ksh)[i] = 0u; ((unsigned*)Qsh)[i] = 0u; ((unsigned*)Vth)[i] = 0u;
  }
  __syncthreads();
  for (int i = tid; i < 4*12*19; i += 256) {
    int h = i / 228, r = i % 228, l = r / 19, t2 = r % 19;
    long off = ((long)(b*L_ + l) * N_ + n) * D_ + h*HD_ + 2*t2;
    *(unsigned*)&Ksh[h][l][2*t2] = *(const unsigned*)(kg + off);
    *(unsigned*)&Qsh[h][l][2*t2] = *(const unsigned*)(qg + off);
  }
  for (int i = tid; i < 4*12*19; i += 256) {
    int h = i / 228, r = i % 228, l = r / 19, t2 = r % 19;
    long off = ((long)(b*L_ + l) * N_ + n) * D_ + h*HD_ + 2*t2;
    unsigned u = *(const unsigned*)(vg + off);
    Vth[h][2*t2][l]     = (ushort)(u & 0xffffu);
    Vth[h][2*t2 + 1][l] = (ushort)(u >> 16);
  }
  __syncthreads();
  int lane = tid & 63, w = tid >> 6;
  int cl = lane & 15, gr = lane >> 4;
  const short8 z8 = {0,0,0,0,0,0,0,0};
  short8 a00 = *(const short8*)&Ksh[w][cl][8*gr];
  short8 qB0 = *(const short8*)&Qsh[w][cl][8*gr];
  short8 a01 = (gr == 0) ? *(const short8*)&Ksh[w][cl][32] : z8;
  short8 qB1 = (gr == 0) ? *(const short8*)&Qsh[w][cl][32] : z8;
  float4v sa = (float4v){0,0,0,0};
  sa = __builtin_amdgcn_mfma_f32_16x16x32_bf16(a00, qB0, sa, 0, 0, 0);
  sa = __builtin_amdgcn_mfma_f32_16x16x32_bf16(a01, qB1, sa, 0, 0, 0);
  float p[4];
#pragma unroll
  for (int r = 0; r < 4; ++r) {
    float xv = (4*gr + r < 12) ? sa[r]*C2_ : -1e30f;
    p[r] = __builtin_exp2f(fminf(xv, 80.f));
  }
  float sum_ = (p[0] + p[1]) + (p[2] + p[3]);
  sum_ += __shfl_xor(sum_, 16, 64);
  sum_ += __shfl_xor(sum_, 32, 64);
  unsigned u0 = pk_bf(p[0], p[1]);
  unsigned u1 = pk_bf(p[2], p[3]);
  int srcA = cl + 32*(gr & 1);
  int srcB = srcA + 16;
  unsigned w0 = __shfl(u0, srcA, 64), w1 = __shfl(u1, srcA, 64);
  unsigned w2 = __shfl(u0, srcB, 64), w3 = __shfl(u1, srcB, 64);
  union { unsigned u[4]; short8 v; } pbu;
  bool gv = gr < 2;
  pbu.u[0] = gv ? w0 : 0u; pbu.u[1] = gv ? w1 : 0u;
  pbu.u[2] = gv ? w2 : 0u; pbu.u[3] = gv ? w3 : 0u;
  short8 pB = pbu.v;
  float4v accO[3];
#pragma unroll
  for (int dt = 0; dt < 3; ++dt) {
    short8 aV = (gv && (dt < 2 || cl < 8))
        ? *(const short8*)&Vth[w][16*dt + cl][8*gr] : z8;
    accO[dt] = (float4v){0,0,0,0};
    accO[dt] = __builtin_amdgcn_mfma_f32_16x16x32_bf16(aV, pB, accO[dt], 0, 0, 0);
  }
  if (cl < 12) {
    float inv = 1.f / sum_;
    bf* ap = a + ((long)(b*L_ + cl) * N_ + n) * D_ + w*HD_;
#pragma unroll
    for (int dt = 0; dt < 2; ++dt) {
      *(unsigned*)(ap + 16*dt + 4*gr)     = pk_bf(accO[dt][0]*inv, accO[dt][1]*inv);
      *(unsigned*)(ap + 16*dt + 4*gr + 2) = pk_bf(accO[dt][2]*inv, accO[dt][3]*inv);
    }
    if (gr == 0) {
      *(unsigned*)(ap + 32) = pk_bf(accO[2][0]*inv, accO[2][1]*inv);
      *(unsigned*)(ap + 34) = pk_bf(accO[2][2]*inv, accO[2][3]*inv);
    } else if (gr == 1) {
      *(unsigned*)(ap + 36) = pk_bf(accO[2][0]*inv, accO[2][1]*inv);
    }
  }
}

/* ------------------------------------------------------------------ */
/* Spatial attention v6b (round-9 proven): one (b,l,h) unit per block. */
__global__ __launch_bounds__(512) void k_attn_s6(
    const ushort* __restrict__ qg, const ushort* __restrict__ kg,
    const ushort* __restrict__ vg, bf* __restrict__ a) {
  __shared__ ushort Ks[360][40];
  __shared__ ushort Vt[38][392];
  int tid = threadIdx.x;
  int lane = tid & 63, w = tid >> 6;
  int cl = lane & 15, gr = lane >> 4;
  bool g0 = (gr == 0);
  const short8 z8 = {0,0,0,0,0,0,0,0};

  int id = blockIdx.x;
  int h = id & 3; int s = id >> 2;
  int b = s / L_; int l = s % L_;
  long base = (long)(b*L_ + l) * N_;
  for (int i = tid; i < 360*20; i += 512) {
    int j = i / 20, t2 = i % 20;
    unsigned u = 0u;
    if (j < N_ && t2 < 19)
      u = *(const unsigned*)(kg + (base + j)*D_ + h*HD_ + 2*t2);
    *(unsigned*)&Ks[j][2*t2] = u;
  }
  for (int i = tid; i < N_*19; i += 512) {
    int j = i / 19, t2 = i % 19;
    unsigned u = *(const unsigned*)(vg + (base + j)*D_ + h*HD_ + 2*t2);
    Vt[2*t2][j]     = (ushort)(u & 0xffffu);
    Vt[2*t2 + 1][j] = (ushort)(u >> 16);
  }
  for (int i = tid; i < 38*26; i += 512)
    Vt[i / 26][N_ + i % 26] = 0;
  __syncthreads();

  for (int qt = w; qt < 23; qt += 8) {
    const ushort* qp = qg + (base + 16*qt + cl) * D_ + h*HD_;
    short8 qB0 = ld_g8(qp + 8*gr);
    short8 qB1 = ld_g8(qp + 32 + 8*gr);
    float sum_ = 0.f;
    float4v accO[3];
    accO[0] = (float4v){0,0,0,0};
    accO[1] = (float4v){0,0,0,0};
    accO[2] = (float4v){0,0,0,0};
#pragma unroll 1
    for (int pr = 0; pr < 11; ++pr) {
      int k0 = 32*pr;
      int kr0 = k0 + cl;
      int kr1 = k0 + 16 + cl;
      float4v s0a = (float4v){0,0,0,0}, s1a = (float4v){0,0,0,0};
      {
        short8 a00 = *(const short8*)&Ks[kr0][8*gr];
        short8 a10 = *(const short8*)&Ks[kr1][8*gr];
        __builtin_amdgcn_s_setprio(1);
        s0a = __builtin_amdgcn_mfma_f32_16x16x32_bf16(a00, qB0, s0a, 0, 0, 0);
        s1a = __builtin_amdgcn_mfma_f32_16x16x32_bf16(a10, qB0, s1a, 0, 0, 0);
        short8 a01 = g0 ? *(const short8*)&Ks[kr0][32] : z8;
        short8 a11 = g0 ? *(const short8*)&Ks[kr1][32] : z8;
        s0a = __builtin_amdgcn_mfma_f32_16x16x32_bf16(a01, qB1, s0a, 0, 0, 0);
        s1a = __builtin_amdgcn_mfma_f32_16x16x32_bf16(a11, qB1, s1a, 0, 0, 0);
        __builtin_amdgcn_s_setprio(0);
      }
      float p0[4], p1[4];
#pragma unroll
      for (int r = 0; r < 4; ++r) {
        p0[r] = __builtin_exp2f(fminf(s0a[r]*C2_, 80.f));
        p1[r] = __builtin_exp2f(fminf(s1a[r]*C2_, 80.f));
      }
      sum_ += (p0[0] + p0[1]) + (p0[2] + p0[3])
            + (p1[0] + p1[1]) + (p1[2] + p1[3]);
      unsigned u0 = pk_bf(p0[0], p0[1]);
      unsigned u1 = pk_bf(p0[2], p0[3]);
      unsigned u2 = pk_bf(p1[0], p1[1]);
      unsigned u3 = pk_bf(p1[2], p1[3]);
      int srcA = cl + 16*((2*gr) & 3);
      int srcB = srcA + 16;
      unsigned a0 = __shfl(u0, srcA, 64), b0 = __shfl(u1, srcA, 64);
      unsigned c0 = __shfl(u0, srcB, 64), d0 = __shfl(u1, srcB, 64);
      unsigned a2 = __shfl(u2, srcA, 64), b2 = __shfl(u3, srcA, 64);
      unsigned c2 = __shfl(u2, srcB, 64), d2 = __shfl(u3, srcB, 64);
      bool lo = gr < 2;
      union { unsigned u[4]; short8 v; } pbu;
      pbu.u[0] = lo ? a0 : a2;
      pbu.u[1] = lo ? b0 : b2;
      pbu.u[2] = lo ? c0 : c2;
      pbu.u[3] = lo ? d0 : d2;
      short8 pB = pbu.v;
      __builtin_amdgcn_s_setprio(1);
#pragma unroll
      for (int dt = 0; dt < 3; ++dt) {
        short8 aV = (dt < 2 || cl < 6)
            ? *(const short8*)&Vt[16*dt + cl][k0 + 8*gr] : z8;
        accO[dt] = __builtin_amdgcn_mfma_f32_16x16x32_bf16(aV, pB, accO[dt], 0, 0, 0);
      }
      __builtin_amdgcn_s_setprio(0);
    }
    { /* tail tile: keys 352..357 */
      int k0 = 352;
      int kr0 = k0 + cl; if (kr0 > 359) kr0 = 359;
      float4v s0a = (float4v){0,0,0,0};
      {
        short8 a00 = *(const short8*)&Ks[kr0][8*gr];
        s0a = __builtin_amdgcn_mfma_f32_16x16x32_bf16(a00, qB0, s0a, 0, 0, 0);
        short8 a01 = g0 ? *(const short8*)&Ks[kr0][32] : z8;
        s0a = __builtin_amdgcn_mfma_f32_16x16x32_bf16(a01, qB1, s0a, 0, 0, 0);
      }
      float p0[4];
#pragma unroll
      for (int r = 0; r < 4; ++r) {
        float xv = (4*gr + r < 6) ? s0a[r]*C2_ : -1e30f;
        p0[r] = __builtin_exp2f(fminf(xv, 80.f));
      }
      sum_ += (p0[0] + p0[1]) + (p0[2] + p0[3]);
      unsigned u0 = pk_bf(p0[0], p0[1]);
      unsigned u1 = pk_bf(p0[2], p0[3]);
      int srcA = cl + 16*((2*gr) & 3);
      int srcB = srcA + 16;
      unsigned a0 = __shfl(u0, srcA, 64), b0 = __shfl(u1, srcA, 64);
      unsigned c0 = __shfl(u0, srcB, 64), d0 = __shfl(u1, srcB, 64);
      bool lo = gr < 2;
      union { unsigned u[4]; short8 v; } pbu;
      pbu.u[0] = lo ? a0 : 0u;
      pbu.u[1] = lo ? b0 : 0u;
      pbu.u[2] = lo ? c0 : 0u;
      pbu.u[3] = lo ? d0 : 0u;
      short8 pB = pbu.v;
#pragma unroll
      for (int dt = 0; dt < 3; ++dt) {
        short8 aV = (dt < 2 || cl < 6)
            ? *(const short8*)&Vt[16*dt + cl][k0 + 8*gr] : z8;
        accO[dt] = __builtin_amdgcn_mfma_f32_16x16x32_bf16(aV, pB, accO[dt], 0, 0, 0);
      }
    }
    sum_ += __shfl_xor(sum_, 16, 64);
    sum_ += __shfl_xor(sum_, 32, 64);
    int qi = 16*qt + cl;
    if (qi < N_) {
      float inv = 1.f / sum_;
      bf* ap = a + (base + qi)*D_ + h*HD_;
#pragma unroll
      for (int dt = 0; dt < 2; ++dt) {
        *(unsigned*)(ap + 16*dt + 4*gr)     = pk_bf(accO[dt][0]*inv, accO[dt][1]*inv);
        *(unsigned*)(ap + 16*dt + 4*gr + 2) = pk_bf(accO[dt][2]*inv, accO[dt][3]*inv);
      }
      if (gr == 0) {
        *(unsigned*)(ap + 32) = pk_bf(accO[2][0]*inv, accO[2][1]*inv);
        *(unsigned*)(ap + 34) = pk_bf(accO[2][2]*inv, accO[2][3]*inv);
      } else if (gr == 1) {
        *(unsigned*)(ap + 36) = pk_bf(accO[2][0]*inv, accO[2][1]*inv);
      }
    }
  }
}

/* ------------------------------------------------------------------ */
__global__ __launch_bounds__(256) void k_evtpool(
    const float* __restrict__ marker, const void* __restrict__ doy_mask,
    const float* __restrict__ evt_h, float* __restrict__ evtp) {
  __shared__ int hasF32, hasBig;
  if (threadIdx.x == 0) { hasF32 = 0; hasBig = 0; }
  __syncthreads();
  const unsigned* mw = (const unsigned*)doy_mask;
  for (int w = threadIdx.x; w < 732; w += 256) {
    unsigned u = mw[w];
    if (u == 0x3F800000u) hasF32 = 1;
    else if (u > 1u) hasBig = 1;
  }
  __syncthreads();
  int fmt = hasF32 ? 2 : (hasBig ? 1 : 0);
  int b = blockIdx.x;
  float m3 = marker[((b*L_ + (L_-1))*N_ + 0)*4 + 3];
  int doy = (int)(m3 * 365.f); doy = doy < 0 ? 0 : (doy > 365 ? 365 : doy);
  int j = threadIdx.x;
  float mx = -1e30f;
  for (int kx = 0; kx < 8; ++kx) {
    bool mk;
    if (fmt == 2)      mk = ((const float*)doy_mask)[doy*8 + kx] != 0.f;
    else if (fmt == 1) mk = ((const unsigned char*)doy_mask)[doy*8 + kx] != 0;
    else               mk = ((const int*)doy_mask)[doy*8 + kx] != 0;
    if (mk) mx = fmaxf(mx, evt_h[(b*8 + kx)*256 + j]);
  }
  evtp[b*256 + j] = mx;
}

/* ------------------------------------------------------------------ */
__global__ __launch_bounds__(192) void k_final3(
    const bf* __restrict__ x, const float* __restrict__ wcomb,
    const float* __restrict__ wevtsum, const float* __restrict__ evtp,
    const float* __restrict__ b_mm, const float* __restrict__ b_ts,
    float* __restrict__ out) {
  int id = blockIdx.x; int b = id / N_; int n = id % N_;
  __shared__ float xs[1824];
  __shared__ float part[16][12];
  int tid = threadIdx.x;
  for (int e = tid; e < 912; e += 192) {
    int l = e / 76, du = e % 76;
    unsigned u = *(const unsigned*)((const ushort*)x +
        (((long)(b*L_ + l) * N_ + n) * 152 + 2*du));
    xs[l*152 + 2*du]     = lo_bf(u);
    xs[l*152 + 2*du + 1] = hi_bf(u);
  }
  __syncthreads();
  int g2 = tid / 12, p = tid % 12;
  float acc = 0.f;
  for (int e = g2; e < 1824; e += 16)
    acc += xs[e] * wcomb[e*12 + p];
  part[g2][p] = acc;
  __syncthreads();
  if (tid < 12) {
    float s = b_mm[tid] + b_ts[tid];
    for (int e = 0; e < 256; ++e) s += evtp[b*256 + e] * wevtsum[e*12 + tid];
    for (int gg = 0; gg < 16; ++gg) s += part[gg][tid];
    out[(b*12 + tid) * N_ + n] = s;
  }
}

/* ------------------------------------------------------------------ */
extern "C" void kernel_launch(void* const* d_in, const int* in_sizes, int n_in,
                              void* d_out, int out_size, void* d_ws, size_t ws_size,
                              hipStream_t stream) {
  static const int expect[32] = {
    68736, 274944, 72, 24, 3456, 168, 343680,
    138624, 912, 138624, 912, 138624, 912, 138624, 912,
    233472, 1536, 233472, 912,
    912, 912, 912, 912,
    4195328, 262144, 256,
    58752, 12, 21888, 12,
    2928, 2928 };
  int nb = (out_size + 255)/256;
  if (n_in != 32) {
    k_beacon<<<nb, 256, 0, stream>>>((float*)d_out, out_size, 998.f);
    return;
  }
  for (int i = 0; i < 32; ++i) {
    if (in_sizes[i] != expect[i]) {
      k_beacon<<<nb, 256, 0, stream>>>((float*)d_out, out_size, 1000.f + i);
      return;
    }
  }
  if (out_size != 68736) {
    k_beacon<<<nb, 256, 0, stream>>>((float*)d_out, out_size, 997.f);
    return;
  }

  const float* var_x  = (const float*)d_in[0];
  const float* marker = (const float*)d_in[1];
  const float* W_in   = (const float*)d_in[2];
  const float* b_in   = (const float*)d_in[3];
  const float* tod    = (const float*)d_in[4];
  const float* dow    = (const float*)d_in[5];
  const float* adap   = (const float*)d_in[6];
  const float* Wq = (const float*)d_in[7];  const float* bq = (const float*)d_in[8];
  const float* Wk = (const float*)d_in[9];  const float* bk = (const float*)d_in[10];
  const float* Wv = (const float*)d_in[11]; const float* bv = (const float*)d_in[12];
  const float* Wo = (const float*)d_in[13]; const float* bo = (const float*)d_in[14];
  const float* W1 = (const float*)d_in[15]; const float* b1 = (const float*)d_in[16];
  const float* W2 = (const float*)d_in[17]; const float* b2 = (const float*)d_in[18];
  const float* g1 = (const float*)d_in[19]; const float* be1 = (const float*)d_in[20];
  const float* g2 = (const float*)d_in[21]; const float* be2 = (const float*)d_in[22];
  const float* emb   = (const float*)d_in[23];
  const float* W_evt = (const float*)d_in[24]; const float* b_evt = (const float*)d_in[25];
  const float* W_mm  = (const float*)d_in[26]; const float* b_mm  = (const float*)d_in[27];
  const float* W_ts  = (const float*)d_in[28]; const float* b_ts  = (const float*)d_in[29];
  const int* doyi = (const int*)d_in[30];
  const void* doym = d_in[31];

  const long TD = (long)TOK_ * D_;
  size_t need = (size_t)TD * 2 * 5
              + (size_t)(32768 + 4096 + 3072 + 21888) * 4
              + 2764800
              + 4096;
  if (ws_size < need) {
    k_beacon<<<nb, 256, 0, stream>>>((float*)d_out, out_size, (float)(ws_size >> 20));
    return;
  }

  bf* x = (bf*)d_ws;
  bf* q = x + TD;
  bf* k = q + TD;
  bf* v = k + TD;
  bf* a = v + TD;
  float* evt_h   = (float*)(a + TD);
  float* evtp    = evt_h + 32768;
  float* wevtsum = evtp + 4096;
  float* wcomb   = wevtsum + 3072;
  ushort* wprep  = (ushort*)(wcomb + 21888);

  k_prep<<<PREP_B, 256, 0, stream>>>(
      Wq, Wk, Wv, Wo, W1, W2, (unsigned*)wprep,
      var_x, marker, W_in, b_in, tod, dow, adap, x,
      doyi, emb, W_evt, b_evt, evt_h,
      W_mm, W_ts, wcomb, wevtsum);
  k_evtpool<<<16, 256, 0, stream>>>(marker, doym, evt_h, evtp);
  for (int i = 0; i < 6; ++i) {
    const ushort* pl = wprep + (size_t)i * 230400;
    /* fused QKV projection (64-tok blocks) */
    k_gemm7<152,152,3,64,1,false,false><<<TOK_/64, 512, 0, stream>>>(
        x, pl, bq + i*152, bk + i*152, bv + i*152,
        nullptr, nullptr, nullptr, q, k, v);
    if (i < 3)
      k_attn_t2<<<B_*N_, 256, 0, stream>>>(
          (const ushort*)q, (const ushort*)k, (const ushort*)v, a);
    else
      k_attn_s6<<<B_*L_*4, 512, 0, stream>>>(
          (const ushort*)q, (const ushort*)k, (const ushort*)v, a);
    /* fused Wo+LN1+FFN+LN2: x = LN2( FF(LN1(a@Wo + bo + x)) + h ) */
    k_layer3<<<TOK_/64, 512, 0, stream>>>(
        a, x, pl + 96000, pl + 128000, pl + 179200,
        bo + i*152, b1 + i*256, b2 + i*152,
        g1 + i*152, be1 + i*152, g2 + i*152, be2 + i*152, x);
  }
  k_final3<<<B_*N_, 192, 0, stream>>>(x, wcomb, wevtsum, evtp, b_mm, b_ts,
                                      (float*)d_out);
}

// Round 14
// 990.944 us; speedup vs baseline: 1.0185x; 1.0185x over previous
//
#include <hip/hip_runtime.h>
#include <hip/hip_bf16.h>

using bf = __hip_bfloat16;

#define B_   16
#define L_   12
#define N_   358
#define D_   152
#define TOK_ (B_*L_*N_)   /* 68736 */
#define FF_  256
#define HD_  38
#define SCALE_ 0.16222142113076254f  /* 38^-0.5 */
#define C2_   0.23403921469340696f   /* SCALE_ * log2(e) */

__device__ __forceinline__ float bf2f(bf x) { return __bfloat162float(x); }
__device__ __forceinline__ bf f2bf(float f) { return __float2bfloat16(f); }
__device__ __forceinline__ float lo_bf(unsigned u) { return __uint_as_float(u << 16); }
__device__ __forceinline__ float hi_bf(unsigned u) { return __uint_as_float(u & 0xffff0000u); }
__device__ __forceinline__ unsigned pk_bf(float a, float b) {
  union { bf h; unsigned short u; } A, Bu;
  A.h = f2bf(a); Bu.h = f2bf(b);
  return ((unsigned)Bu.u << 16) | A.u;
}
__device__ __forceinline__ ushort f2bf_u(float f) {
  union { bf h; ushort u; } t; t.h = f2bf(f); return t.u;
}

using short8  = __attribute__((ext_vector_type(8))) short;
using float4v = __attribute__((ext_vector_type(4))) float;

/* async global->LDS, 16B per lane; dst is wave-uniform base (HW adds lane*16) */
__device__ __forceinline__ void gl_lds16(const void* g, void* l) {
  __builtin_amdgcn_global_load_lds(
      (const __attribute__((address_space(1))) void*)g,
      (__attribute__((address_space(3))) void*)l, 16, 0, 0);
}

/* copy SUBCB bytes global->LDS; 8 waves interleave 1024B blocks */
template<int SUBCB>
__device__ __forceinline__ void issue_w8(const char* gsrc, ushort* lds, int w, int lane) {
  constexpr int TB = SUBCB >> 10;
  constexpr int TAIL = SUBCB & 1023;
#pragma unroll
  for (int blk0 = 0; blk0 < TB; blk0 += 8) {
    int blk = blk0 + w;
    if (blk < TB)
      gl_lds16(gsrc + blk*1024 + (size_t)lane*16, (char*)lds + blk*1024);
  }
  if (TAIL) {
    if (w == (TB & 7) && lane < TAIL/16)
      gl_lds16(gsrc + TB*1024 + (size_t)lane*16, (char*)lds + TB*1024);
  }
}

/* per-wave count of gl_lds16 issues done by issue_w8<SUBCB> (wave-uniform) */
template<int SUBCB>
__device__ __forceinline__ int issue_cnt(int w) {
  constexpr int TB = SUBCB >> 10;
  constexpr int TAIL = SUBCB & 1023;
  int n = (TB > 8 && w < TB - 8) ? 2 : 1;
  if (TAIL && w == (TB & 7)) n += 1;
  return n;
}

/* counted-vmcnt wait: keep newest n loads in flight (n in {1,2,3}) */
__device__ __forceinline__ void vm_wait(int n) {
  if (n == 1)      asm volatile("s_waitcnt vmcnt(1)" ::: "memory");
  else if (n == 2) asm volatile("s_waitcnt vmcnt(2)" ::: "memory");
  else             asm volatile("s_waitcnt vmcnt(3)" ::: "memory");
}

/* 16B logical load from a 4B-aligned (not necessarily 16B-aligned) address */
__device__ __forceinline__ short8 ld_g8(const ushort* p) {
  union { unsigned u[4]; short8 v; } t;
  t.u[0] = *(const unsigned*)(p);
  t.u[1] = *(const unsigned*)(p + 2);
  t.u[2] = *(const unsigned*)(p + 4);
  t.u[3] = *(const unsigned*)(p + 6);
  return t.v;
}

/* ------------------------------------------------------------------ */
__global__ void k_beacon(float* out, int n, float val) {
  int i = blockIdx.x * 256 + threadIdx.x;
  if (i < n) out[i] = val;
}

/* ================= fused prep: wprep | embed | evt1 | wcomb =======
   wprep: 4 output words per thread (jj-unrolled) -> 4x memory-level
   parallelism in the latency-bound strided-read region. Per-index
   body identical to the proven decoder.                              */
#define WPREP_B 675      /* ceil(691200 / 1024) */
#define EMB_B   269
#define EVT_B   128
#define WC_B    86
#define PREP_B  (WPREP_B + EMB_B + EVT_B + WC_B)   /* 1158 */

__device__ void d_wprep(int bid, int tid,
    const float* __restrict__ Wq, const float* __restrict__ Wk,
    const float* __restrict__ Wv, const float* __restrict__ Wo,
    const float* __restrict__ W1, const float* __restrict__ W2,
    unsigned* __restrict__ out) {
#pragma unroll
  for (int jj = 0; jj < 4; ++jj) {
    int i = bid * 1024 + jj * 256 + tid;
    if (i >= 6*115200) continue;
    int layer = i / 115200, r = i % 115200;
    const float* src; int K, Nd, d, up, c;
    if (r < 48000) {
      c = r / 9600; int rr = r % 9600; int m = rr / 3200; int r2 = rr % 3200;
      d = r2 / 20; up = r2 % 20;
      src = (m == 0 ? Wq : (m == 1 ? Wk : Wv)) + layer*23104; K = 152; Nd = 152;
    } else if (r < 64000) {
      int rr = r - 48000; c = rr / 3200; int r2 = rr % 3200;
      d = r2 / 20; up = r2 % 20;
      src = Wo + layer*23104; K = 152; Nd = 152;
    } else if (r < 89600) {
      int rr = r - 64000; c = rr / 5120; int r2 = rr % 5120;
      d = r2 / 20; up = r2 % 20;
      src = W1 + layer*38912; K = 152; Nd = 256;
    } else {
      int rr = r - 89600; c = rr / 3200; int r2 = rr % 3200;
      d = r2 / 20; up = r2 % 20;
      src = W2 + layer*38912; K = 256; Nd = 152;
    }
    float v0 = 0.f, v1 = 0.f;
    int k0 = 32*c + 2*up;
    if (up < 16 && d < Nd) {
      if (k0 < K)     v0 = src[(long)k0*Nd + d];
      if (k0 + 1 < K) v1 = src[(long)(k0+1)*Nd + d];
    }
    out[i] = pk_bf(v0, v1);
  }
}

__device__ void d_embed(int bid, int tid,
    const float* __restrict__ var_x, const float* __restrict__ marker,
    const float* __restrict__ W_in, const float* __restrict__ b_in,
    const float* __restrict__ tod_emb, const float* __restrict__ dow_emb,
    const float* __restrict__ adap, bf* __restrict__ x) {
  int t = bid * 256 + tid;
  if (t >= TOK_) return;
  int n = t % N_;
  int l = (t / N_) % L_;
  float var = var_x[t];
  float m0 = marker[t*4 + 0];
  float m1 = marker[t*4 + 1];
  int tod = (int)(m0 * 144.f); tod = tod < 0 ? 0 : (tod > 143 ? 143 : tod);
  int dw  = (int)(m1 * 7.f);   dw  = dw  < 0 ? 0 : (dw  > 6   ? 6   : dw);
  bf* xp = x + (long)t * D_;
  for (int d = 0; d < 24; ++d)
    xp[d] = f2bf(var * W_in[d] + m0 * W_in[24 + d] + m1 * W_in[48 + d] + b_in[d]);
  for (int d = 0; d < 24; ++d) xp[24 + d] = f2bf(tod_emb[tod*24 + d]);
  for (int d = 0; d < 24; ++d) xp[48 + d] = f2bf(dow_emb[dw*24 + d]);
  for (int d = 0; d < 80; ++d) xp[72 + d] = f2bf(adap[(l*N_ + n)*80 + d]);
}

__device__ void d_evt1(int bk, int tid,
    const float* __restrict__ marker, const int* __restrict__ doy_idx,
    const float* __restrict__ emb, const float* __restrict__ W_evt,
    const float* __restrict__ b_evt, float* __restrict__ evt_h) {
  int b = bk >> 3; int ks = bk & 7;
  float m3 = marker[((b*L_ + (L_-1))*N_ + 0)*4 + 3];
  int doy = (int)(m3 * 365.f); doy = doy < 0 ? 0 : (doy > 365 ? 365 : doy);
  int idx = doy_idx[doy*8 + ks];
  if (idx < 0 || idx > 4096) idx = 0;
  int d = tid;
  float acc = b_evt[d];
  const float* er = emb + (long)idx * 1024;
  for (int e = 0; e < 1024; ++e)
    acc += er[e] * W_evt[e*256 + d];
  evt_h[bk*256 + d] = acc;
}

__device__ void d_wcomb(int bid, int tid,
    const float* __restrict__ W_mm, const float* __restrict__ W_ts,
    float* __restrict__ wcomb, float* __restrict__ wevtsum) {
  int i = bid * 256 + tid;
  if (i < 1824*12) {
    int r = i / 12, p = i % 12, l = r / 152, d = r % 152;
    wcomb[i] = W_mm[(l*408 + 256 + d)*12 + p] + W_ts[i];
  }
  if (i < 256*12) {
    int e = i / 12, p = i % 12;
    float s = 0.f;
    for (int l = 0; l < 12; ++l) s += W_mm[(l*408 + e)*12 + p];
    wevtsum[i] = s;
  }
}

__global__ __launch_bounds__(256) void k_prep(
    const float* Wq, const float* Wk, const float* Wv, const float* Wo,
    const float* W1, const float* W2, unsigned* wout,
    const float* var_x, const float* marker, const float* W_in,
    const float* b_in, const float* tod_emb, const float* dow_emb,
    const float* adap, bf* x,
    const int* doyi, const float* emb, const float* W_evt,
    const float* b_evt, float* evt_h,
    const float* W_mm, const float* W_ts, float* wcomb, float* wevtsum) {
  int bid = blockIdx.x, tid = threadIdx.x;
  if (bid < WPREP_B)
    d_wprep(bid, tid, Wq, Wk, Wv, Wo, W1, W2, wout);
  else if (bid < WPREP_B + EMB_B)
    d_embed(bid - WPREP_B, tid, var_x, marker, W_in, b_in, tod_emb, dow_emb, adap, x);
  else if (bid < WPREP_B + EMB_B + EVT_B)
    d_evt1(bid - WPREP_B - EMB_B, tid, marker, doyi, emb, W_evt, b_evt, evt_h);
  else
    d_wcomb(bid - WPREP_B - EMB_B - EVT_B, tid, W_mm, W_ts, wcomb, wevtsum);
}

/* ------------------------------------------------------------------ */
/* GEMM v8 (round-7/9 proven): counted-vmcnt two-barrier K-loop.
   Used only for the fused QKV projection.                            */
template<int K, int Nd, int NW, int TOKB, int CSPLIT, bool RELU, bool LN>
__global__ __launch_bounds__(512) void k_gemm7(
    const bf* __restrict__ X, const ushort* __restrict__ Wg,
    const float* __restrict__ bi0, const float* __restrict__ bi1,
    const float* __restrict__ bi2, const bf* __restrict__ Res,
    const float* __restrict__ g, const float* __restrict__ bb,
    bf* __restrict__ Y0, bf* __restrict__ Y1, bf* __restrict__ Y2) {
  constexpr int NJ   = (Nd + 15) / 16;
  constexpr int NdP  = NJ * 16;
  constexpr int KC   = (K + 31) / 32;
  constexpr int G    = NW * CSPLIT;
  constexpr int S    = KC * G;
  constexpr int IR   = NdP / CSPLIT;
  constexpr int SUB_USH = IR * 40;
  constexpr int SUBCB   = SUB_USH * 2;
  constexpr int NJW  = IR / 32;
  constexpr int MR   = TOKB / 64;
  constexpr bool GLX = (K == 152);
  constexpr int XSTR = GLX ? K : (K + 8);
  __shared__ __align__(16) ushort Xs[TOKB * XSTR + 8];
  __shared__ __align__(16) ushort Wb[2 * SUB_USH];
  long row0 = (long)blockIdx.x * TOKB;
  int tid = threadIdx.x;
  int lane = tid & 63, w = tid >> 6;
  int cl = lane & 15, gr = lane >> 4;
  int wr = w >> 1, wc = w & 1;
  if constexpr (GLX) {
    constexpr int TBX = TOKB * K * 2 / 1024;
    const char* Xgc = (const char*)(X + row0 * K);
#pragma unroll
    for (int b0 = 0; b0 < TBX; b0 += 8) {
      int blk = b0 + w;
      if (blk < TBX)
        gl_lds16(Xgc + blk*1024 + (size_t)lane*16, (char*)Xs + blk*1024);
    }
  } else {
    const char* Xgc = (const char*)(X + row0 * K);
    for (int i = tid; i < TOKB*(K/8); i += 512) {
      int r = i / (K/8), c = i % (K/8);
      *(short8*)&Xs[r*XSTR + 8*c] = *(const short8*)(Xgc + r*(K*2) + c*16);
    }
    __syncthreads();
  }
  const char* gW = (const char*)Wg;
  issue_w8<SUBCB>(gW, Wb, w, lane);
  const int nw = issue_cnt<SUBCB>(w);
  float4v acc[G][MR][NJW];
#pragma unroll
  for (int gi = 0; gi < G; ++gi)
#pragma unroll
    for (int mi = 0; mi < MR; ++mi)
#pragma unroll
      for (int j = 0; j < NJW; ++j) acc[gi][mi][j] = (float4v){0.f,0.f,0.f,0.f};
#pragma unroll
  for (int s = 0; s < S; ++s) {
    if (s + 1 < S) {
      issue_w8<SUBCB>(gW + (size_t)(s+1)*SUBCB, Wb + ((s+1)&1)*SUB_USH, w, lane);
      vm_wait(nw);
    } else {
      asm volatile("s_waitcnt vmcnt(0)" ::: "memory");
    }
    __builtin_amdgcn_s_barrier();
    int kc = (s / G) * 32;
    const ushort* wb = Wb + (s&1)*SUB_USH;
    short8 af[MR];
#pragma unroll
    for (int mi = 0; mi < MR; ++mi)
      af[mi] = *(const short8*)&Xs[((TOKB/4)*wr + 16*mi + cl)*XSTR + kc + 8*gr];
#pragma unroll
    for (int j = 0; j < NJW; ++j) {
      short8 bv = *(const short8*)&wb[((IR/2)*wc + 16*j + cl)*40 + 8*gr];
#pragma unroll
      for (int mi = 0; mi < MR; ++mi)
        acc[s % G][mi][j] =
            __builtin_amdgcn_mfma_f32_16x16x32_bf16(af[mi], bv, acc[s % G][mi][j], 0, 0, 0);
    }
    asm volatile("s_waitcnt lgkmcnt(0)" ::: "memory");
    __builtin_amdgcn_s_barrier();
  }
  if constexpr (!LN) {
#pragma unroll
    for (int gi = 0; gi < G; ++gi) {
      bf* Y = (NW > 1) ? (gi == 0 ? Y0 : (gi == 1 ? Y1 : Y2)) : Y0;
      const float* bp = (NW > 1) ? (gi == 0 ? bi0 : (gi == 1 ? bi1 : bi2)) : bi0;
      int colb = (CSPLIT > 1 ? IR*gi : 0) + (IR/2)*wc;
#pragma unroll
      for (int j = 0; j < NJW; ++j) {
        int col = colb + 16*j + cl;
        if (col < Nd) {
          float bvs = bp[col];
#pragma unroll
          for (int mi = 0; mi < MR; ++mi) {
            long rw = row0 + (TOKB/4)*wr + 16*mi + 4*gr;
#pragma unroll
            for (int r = 0; r < 4; ++r) {
              float val = acc[gi][mi][j][r] + bvs;
              if (RELU) val = fmaxf(val, 0.f);
              Y[(rw + r) * Nd + col] = f2bf(val);
            }
          }
        }
      }
    }
  } else {
    float* LNb = (float*)Wb;
    int colb = (IR/2)*wc;
#pragma unroll
    for (int j = 0; j < NJW; ++j) {
      int col = colb + 16*j + cl;
      if (col < Nd) {
        float bvs = bi0[col];
#pragma unroll
        for (int mi = 0; mi < MR; ++mi) {
          long rw = row0 + (TOKB/4)*wr + 16*mi + 4*gr;
#pragma unroll
          for (int r = 0; r < 4; ++r)
            acc[0][mi][j][r] += bvs + bf2f(Res[(rw + r) * Nd + col]);
        }
      }
    }
    float mean[MR][4], rs[MR][4];
#pragma unroll
    for (int mi = 0; mi < MR; ++mi)
#pragma unroll
      for (int r = 0; r < 4; ++r) {
        float s = 0.f;
#pragma unroll
        for (int j = 0; j < NJW; ++j) s += acc[0][mi][j][r];
        s += __shfl_xor(s, 1, 64); s += __shfl_xor(s, 2, 64);
        s += __shfl_xor(s, 4, 64); s += __shfl_xor(s, 8, 64);
        if (cl == 0) LNb[((wr*MR + mi)*2 + wc)*16 + 4*gr + r] = s;
      }
    __syncthreads();
#pragma unroll
    for (int mi = 0; mi < MR; ++mi)
#pragma unroll
      for (int r = 0; r < 4; ++r) {
        float tot = LNb[((wr*MR + mi)*2 + 0)*16 + 4*gr + r]
                  + LNb[((wr*MR + mi)*2 + 1)*16 + 4*gr + r];
        mean[mi][r] = tot * (1.f / (float)Nd);
      }
#pragma unroll
    for (int mi = 0; mi < MR; ++mi)
#pragma unroll
      for (int r = 0; r < 4; ++r) {
        float s2 = 0.f;
#pragma unroll
        for (int j = 0; j < NJW; ++j) {
          int col = colb + 16*j + cl;
          if (col < Nd) {
            float dv = acc[0][mi][j][r] - mean[mi][r];
            s2 += dv*dv;
          }
        }
        s2 += __shfl_xor(s2, 1, 64); s2 += __shfl_xor(s2, 2, 64);
        s2 += __shfl_xor(s2, 4, 64); s2 += __shfl_xor(s2, 8, 64);
        if (cl == 0) LNb[256 + ((wr*MR + mi)*2 + wc)*16 + 4*gr + r] = s2;
      }
    __syncthreads();
#pragma unroll
    for (int mi = 0; mi < MR; ++mi)
#pragma unroll
      for (int r = 0; r < 4; ++r) {
        float tot2 = LNb[256 + ((wr*MR + mi)*2 + 0)*16 + 4*gr + r]
                   + LNb[256 + ((wr*MR + mi)*2 + 1)*16 + 4*gr + r];
        rs[mi][r] = rsqrtf(tot2 * (1.f / (float)Nd) + 1e-5f);
      }
#pragma unroll
    for (int j = 0; j < NJW; ++j) {
      int col = colb + 16*j + cl;
      if (col < Nd) {
        float gv = g[col], bv2 = bb[col];
#pragma unroll
        for (int mi = 0; mi < MR; ++mi) {
          long rw = row0 + (TOKB/4)*wr + 16*mi + 4*gr;
#pragma unroll
          for (int r = 0; r < 4; ++r)
            Y0[(rw + r) * Nd + col] =
                f2bf((acc[0][mi][j][r] - mean[mi][r]) * rs[mi][r] * gv + bv2);
        }
      }
    }
  }
}

/* ------------------------------------------------------------------ */
/* k_layer3 (round-11 proven): fused Wo+LN1+FF1+ReLU+FF2+LN2.
   ALL sync = __syncthreads() (full per-wave vmcnt+lgkmcnt drain).    */
__global__ __launch_bounds__(512) void k_layer3(
    const bf* __restrict__ A, const bf* __restrict__ Xres,
    const ushort* __restrict__ Wog, const ushort* __restrict__ W1g,
    const ushort* __restrict__ W2g,
    const float* __restrict__ bo, const float* __restrict__ b1,
    const float* __restrict__ b2,
    const float* __restrict__ g1v, const float* __restrict__ be1,
    const float* __restrict__ g2v, const float* __restrict__ be2,
    bf* __restrict__ Y) {
  constexpr int S0 = 5,  SUB0 = 6400;
  constexpr int S1 = 10, SUB1 = 5120;
  constexpr int S2 = 8,  SUB2 = 6400;
  constexpr int HSTR = 260;
  __shared__ __align__(16) ushort S_[29440];
  ushort* Xs  = S_;
  ushort* W0b = S_ + 9728;
  ushort* W1b = S_ + 9728;
  ushort* Hs2 = S_;
  ushort* W2b = S_ + 16640;
  float*  LNb1 = (float*)(S_ + 22528);
  long row0 = (long)blockIdx.x * 64;
  int tid = threadIdx.x, lane = tid & 63, w = tid >> 6;
  int cl = lane & 15, gr = lane >> 4;
  int wr = w >> 1, wc = w & 1;
  int colb = 80*wc;
  {
    const char* Agc = (const char*)(A + row0 * 152);
#pragma unroll
    for (int b0 = 0; b0 < 19; b0 += 8) {
      int blk = b0 + w;
      if (blk < 19)
        gl_lds16(Agc + blk*1024 + (size_t)lane*16, (char*)Xs + blk*1024);
    }
  }
  issue_w8<SUB0*2>((const char*)Wog, W0b, w, lane);
  __syncthreads();
  float4v acc0[5];
#pragma unroll
  for (int j = 0; j < 5; ++j) acc0[j] = (float4v){0.f,0.f,0.f,0.f};
#pragma unroll
  for (int s = 0; s < S0; ++s) {
    if (s + 1 < S0)
      issue_w8<SUB0*2>((const char*)Wog + (size_t)(s+1)*SUB0*2,
                       W0b + ((s+1)&1)*SUB0, w, lane);
    int kc = s * 32;
    const ushort* wb = W0b + (s&1)*SUB0;
    short8 af = *(const short8*)&Xs[(16*wr + cl)*152 + kc + 8*gr];
#pragma unroll
    for (int j = 0; j < 5; ++j) {
      short8 bv = *(const short8*)&wb[(80*wc + 16*j + cl)*40 + 8*gr];
      acc0[j] =
          __builtin_amdgcn_mfma_f32_16x16x32_bf16(af, bv, acc0[j], 0, 0, 0);
    }
    __syncthreads();
  }
#pragma unroll
  for (int j = 0; j < 5; ++j) {
    int col = colb + 16*j + cl;
    if (col < D_) {
      float bvs = bo[col];
#pragma unroll
      for (int r = 0; r < 4; ++r)
        acc0[j][r] += bvs + bf2f(Xres[(row0 + 16*wr + 4*gr + r) * D_ + col]);
    }
  }
  float mean1[4], rsv1[4];
#pragma unroll
  for (int r = 0; r < 4; ++r) {
    float s = 0.f;
#pragma unroll
    for (int j = 0; j < 5; ++j)
      if (colb + 16*j + cl < D_) s += acc0[j][r];
    s += __shfl_xor(s, 1, 64); s += __shfl_xor(s, 2, 64);
    s += __shfl_xor(s, 4, 64); s += __shfl_xor(s, 8, 64);
    if (cl == 0) LNb1[(wr*2 + wc)*16 + 4*gr + r] = s;
  }
  __syncthreads();
#pragma unroll
  for (int r = 0; r < 4; ++r) {
    float tot = LNb1[(wr*2 + 0)*16 + 4*gr + r] + LNb1[(wr*2 + 1)*16 + 4*gr + r];
    mean1[r] = tot * (1.f / (float)D_);
  }
#pragma unroll
  for (int r = 0; r < 4; ++r) {
    float s2 = 0.f;
#pragma unroll
    for (int j = 0; j < 5; ++j) {
      int col = colb + 16*j + cl;
      if (col < D_) { float dv = acc0[j][r] - mean1[r]; s2 += dv*dv; }
    }
    s2 += __shfl_xor(s2, 1, 64); s2 += __shfl_xor(s2, 2, 64);
    s2 += __shfl_xor(s2, 4, 64); s2 += __shfl_xor(s2, 8, 64);
    if (cl == 0) LNb1[128 + (wr*2 + wc)*16 + 4*gr + r] = s2;
  }
  __syncthreads();
#pragma unroll
  for (int r = 0; r < 4; ++r) {
    float tot2 = LNb1[128 + (wr*2 + 0)*16 + 4*gr + r]
               + LNb1[128 + (wr*2 + 1)*16 + 4*gr + r];
    rsv1[r] = rsqrtf(tot2 * (1.f / (float)D_) + 1e-5f);
  }
  unsigned hres[5][2];
#pragma unroll
  for (int j = 0; j < 5; ++j) {
    int col = colb + 16*j + cl;
    if (col < D_) {
      float gv = g1v[col], bv2 = be1[col];
      ushort u[4];
#pragma unroll
      for (int r = 0; r < 4; ++r) {
        u[r] = f2bf_u((acc0[j][r] - mean1[r]) * rsv1[r] * gv + bv2);
        Xs[(16*wr + 4*gr + r)*152 + col] = u[r];
      }
      hres[j][0] = (unsigned)u[0] | ((unsigned)u[1] << 16);
      hres[j][1] = (unsigned)u[2] | ((unsigned)u[3] << 16);
    } else {
      hres[j][0] = 0u; hres[j][1] = 0u;
    }
  }
  issue_w8<SUB1*2>((const char*)W1g, W1b, w, lane);
  __syncthreads();
  float4v acc1[2][4];
#pragma unroll
  for (int g2 = 0; g2 < 2; ++g2)
#pragma unroll
    for (int j = 0; j < 4; ++j) acc1[g2][j] = (float4v){0.f,0.f,0.f,0.f};
#pragma unroll
  for (int s = 0; s < S1; ++s) {
    if (s + 1 < S1)
      issue_w8<SUB1*2>((const char*)W1g + (size_t)(s+1)*SUB1*2,
                       W1b + ((s+1)&1)*SUB1, w, lane);
    int kc = (s / 2) * 32;
    const ushort* wb = W1b + (s&1)*SUB1;
    short8 af = *(const short8*)&Xs[(16*wr + cl)*152 + kc + 8*gr];
#pragma unroll
    for (int j = 0; j < 4; ++j) {
      short8 bv = *(const short8*)&wb[(64*wc + 16*j + cl)*40 + 8*gr];
      acc1[s&1][j] =
          __builtin_amdgcn_mfma_f32_16x16x32_bf16(af, bv, acc1[s&1][j], 0, 0, 0);
    }
    __syncthreads();
  }
#pragma unroll
  for (int g2 = 0; g2 < 2; ++g2)
#pragma unroll
    for (int j = 0; j < 4; ++j) {
      int col = g2*128 + 64*wc + 16*j + cl;
      float bvs = b1[col];
#pragma unroll
      for (int r = 0; r < 4; ++r) {
        int row = 16*wr + 4*gr + r;
        Hs2[row*HSTR + col] = f2bf_u(fmaxf(acc1[g2][j][r] + bvs, 0.f));
      }
    }
  issue_w8<SUB2*2>((const char*)W2g, W2b, w, lane);
  __syncthreads();
  float4v acc2[5];
#pragma unroll
  for (int j = 0; j < 5; ++j) acc2[j] = (float4v){0.f,0.f,0.f,0.f};
#pragma unroll
  for (int s = 0; s < S2; ++s) {
    if (s + 1 < S2)
      issue_w8<SUB2*2>((const char*)W2g + (size_t)(s+1)*SUB2*2,
                       W2b + ((s+1)&1)*SUB2, w, lane);
    int kc = s * 32;
    const ushort* wb = W2b + (s&1)*SUB2;
    short8 af = *(const short8*)&Hs2[(16*wr + cl)*HSTR + kc + 8*gr];
#pragma unroll
    for (int j = 0; j < 5; ++j) {
      short8 bv = *(const short8*)&wb[(80*wc + 16*j + cl)*40 + 8*gr];
      acc2[j] =
          __builtin_amdgcn_mfma_f32_16x16x32_bf16(af, bv, acc2[j], 0, 0, 0);
    }
    __syncthreads();
  }
  float* LNb = (float*)W2b;
#pragma unroll
  for (int j = 0; j < 5; ++j) {
    int col = colb + 16*j + cl;
    if (col < D_) {
      float bvs = b2[col];
#pragma unroll
      for (int r = 0; r < 4; ++r)
        acc2[j][r] += bvs + ((r & 1) ? hi_bf(hres[j][r>>1]) : lo_bf(hres[j][r>>1]));
    }
  }
  float mean[4], rsv[4];
#pragma unroll
  for (int r = 0; r < 4; ++r) {
    float s = 0.f;
#pragma unroll
    for (int j = 0; j < 5; ++j)
      if (colb + 16*j + cl < D_) s += acc2[j][r];
    s += __shfl_xor(s, 1, 64); s += __shfl_xor(s, 2, 64);
    s += __shfl_xor(s, 4, 64); s += __shfl_xor(s, 8, 64);
    if (cl == 0) LNb[(wr*2 + wc)*16 + 4*gr + r] = s;
  }
  __syncthreads();
#pragma unroll
  for (int r = 0; r < 4; ++r) {
    float tot = LNb[(wr*2 + 0)*16 + 4*gr + r] + LNb[(wr*2 + 1)*16 + 4*gr + r];
    mean[r] = tot * (1.f / (float)D_);
  }
#pragma unroll
  for (int r = 0; r < 4; ++r) {
    float s2 = 0.f;
#pragma unroll
    for (int j = 0; j < 5; ++j) {
      int col = colb + 16*j + cl;
      if (col < D_) { float dv = acc2[j][r] - mean[r]; s2 += dv*dv; }
    }
    s2 += __shfl_xor(s2, 1, 64); s2 += __shfl_xor(s2, 2, 64);
    s2 += __shfl_xor(s2, 4, 64); s2 += __shfl_xor(s2, 8, 64);
    if (cl == 0) LNb[128 + (wr*2 + wc)*16 + 4*gr + r] = s2;
  }
  __syncthreads();
#pragma unroll
  for (int r = 0; r < 4; ++r) {
    float tot2 = LNb[128 + (wr*2 + 0)*16 + 4*gr + r]
               + LNb[128 + (wr*2 + 1)*16 + 4*gr + r];
    rsv[r] = rsqrtf(tot2 * (1.f / (float)D_) + 1e-5f);
  }
#pragma unroll
  for (int j = 0; j < 5; ++j) {
    int col = colb + 16*j + cl;
    if (col < D_) {
      float gv = g2v[col], bv2 = be2[col];
#pragma unroll
      for (int r = 0; r < 4; ++r)
        Y[(row0 + 16*wr + 4*gr + r) * D_ + col] =
            f2bf((acc2[j][r] - mean[r]) * rsv[r] * gv + bv2);
    }
  }
}

/* ------------------------------------------------------------------ */
/* Temporal attention v2 (round-5 proven): MFMA swapped-operand.      */
__global__ __launch_bounds__(256) void k_attn_t2(
    const ushort* __restrict__ qg, const ushort* __restrict__ kg,
    const ushort* __restrict__ vg, bf* __restrict__ a) {
  int id = blockIdx.x; int b = id / N_; int n = id % N_;
  __shared__ ushort Ksh[4][16][40];
  __shared__ ushort Qsh[4][16][40];
  __shared__ ushort Vth[4][40][16];
  int tid = threadIdx.x;
  for (int i = tid; i < 1280; i += 256) {
    ((unsigned*)Ksh)[i] = 0u; ((unsigned*)Qsh)[i] = 0u; ((unsigned*)Vth)[i] = 0u;
  }
  __syncthreads();
  for (int i = tid; i < 4*12*19; i += 256) {
    int h = i / 228, r = i % 228, l = r / 19, t2 = r % 19;
    long off = ((long)(b*L_ + l) * N_ + n) * D_ + h*HD_ + 2*t2;
    *(unsigned*)&Ksh[h][l][2*t2] = *(const unsigned*)(kg + off);
    *(unsigned*)&Qsh[h][l][2*t2] = *(const unsigned*)(qg + off);
  }
  for (int i = tid; i < 4*12*19; i += 256) {
    int h = i / 228, r = i % 228, l = r / 19, t2 = r % 19;
    long off = ((long)(b*L_ + l) * N_ + n) * D_ + h*HD_ + 2*t2;
    unsigned u = *(const unsigned*)(vg + off);
    Vth[h][2*t2][l]     = (ushort)(u & 0xffffu);
    Vth[h][2*t2 + 1][l] = (ushort)(u >> 16);
  }
  __syncthreads();
  int lane = tid & 63, w = tid >> 6;
  int cl = lane & 15, gr = lane >> 4;
  const short8 z8 = {0,0,0,0,0,0,0,0};
  short8 a00 = *(const short8*)&Ksh[w][cl][8*gr];
  short8 qB0 = *(const short8*)&Qsh[w][cl][8*gr];
  short8 a01 = (gr == 0) ? *(const short8*)&Ksh[w][cl][32] : z8;
  short8 qB1 = (gr == 0) ? *(const short8*)&Qsh[w][cl][32] : z8;
  float4v sa = (float4v){0,0,0,0};
  sa = __builtin_amdgcn_mfma_f32_16x16x32_bf16(a00, qB0, sa, 0, 0, 0);
  sa = __builtin_amdgcn_mfma_f32_16x16x32_bf16(a01, qB1, sa, 0, 0, 0);
  float p[4];
#pragma unroll
  for (int r = 0; r < 4; ++r) {
    float xv = (4*gr + r < 12) ? sa[r]*C2_ : -1e30f;
    p[r] = __builtin_exp2f(fminf(xv, 80.f));
  }
  float sum_ = (p[0] + p[1]) + (p[2] + p[3]);
  sum_ += __shfl_xor(sum_, 16, 64);
  sum_ += __shfl_xor(sum_, 32, 64);
  unsigned u0 = pk_bf(p[0], p[1]);
  unsigned u1 = pk_bf(p[2], p[3]);
  int srcA = cl + 32*(gr & 1);
  int srcB = srcA + 16;
  unsigned w0 = __shfl(u0, srcA, 64), w1 = __shfl(u1, srcA, 64);
  unsigned w2 = __shfl(u0, srcB, 64), w3 = __shfl(u1, srcB, 64);
  union { unsigned u[4]; short8 v; } pbu;
  bool gv = gr < 2;
  pbu.u[0] = gv ? w0 : 0u; pbu.u[1] = gv ? w1 : 0u;
  pbu.u[2] = gv ? w2 : 0u; pbu.u[3] = gv ? w3 : 0u;
  short8 pB = pbu.v;
  float4v accO[3];
#pragma unroll
  for (int dt = 0; dt < 3; ++dt) {
    short8 aV = (gv && (dt < 2 || cl < 8))
        ? *(const short8*)&Vth[w][16*dt + cl][8*gr] : z8;
    accO[dt] = (float4v){0,0,0,0};
    accO[dt] = __builtin_amdgcn_mfma_f32_16x16x32_bf16(aV, pB, accO[dt], 0, 0, 0);
  }
  if (cl < 12) {
    float inv = 1.f / sum_;
    bf* ap = a + ((long)(b*L_ + cl) * N_ + n) * D_ + w*HD_;
#pragma unroll
    for (int dt = 0; dt < 2; ++dt) {
      *(unsigned*)(ap + 16*dt + 4*gr)     = pk_bf(accO[dt][0]*inv, accO[dt][1]*inv);
      *(unsigned*)(ap + 16*dt + 4*gr + 2) = pk_bf(accO[dt][2]*inv, accO[dt][3]*inv);
    }
    if (gr == 0) {
      *(unsigned*)(ap + 32) = pk_bf(accO[2][0]*inv, accO[2][1]*inv);
      *(unsigned*)(ap + 34) = pk_bf(accO[2][2]*inv, accO[2][3]*inv);
    } else if (gr == 1) {
      *(unsigned*)(ap + 36) = pk_bf(accO[2][0]*inv, accO[2][1]*inv);
    }
  }
}

/* ------------------------------------------------------------------ */
/* Spatial attention v6b (round-9 proven): one (b,l,h) unit per block. */
__global__ __launch_bounds__(512) void k_attn_s6(
    const ushort* __restrict__ qg, const ushort* __restrict__ kg,
    const ushort* __restrict__ vg, bf* __restrict__ a) {
  __shared__ ushort Ks[360][40];
  __shared__ ushort Vt[38][392];
  int tid = threadIdx.x;
  int lane = tid & 63, w = tid >> 6;
  int cl = lane & 15, gr = lane >> 4;
  bool g0 = (gr == 0);
  const short8 z8 = {0,0,0,0,0,0,0,0};

  int id = blockIdx.x;
  int h = id & 3; int s = id >> 2;
  int b = s / L_; int l = s % L_;
  long base = (long)(b*L_ + l) * N_;
  for (int i = tid; i < 360*20; i += 512) {
    int j = i / 20, t2 = i % 20;
    unsigned u = 0u;
    if (j < N_ && t2 < 19)
      u = *(const unsigned*)(kg + (base + j)*D_ + h*HD_ + 2*t2);
    *(unsigned*)&Ks[j][2*t2] = u;
  }
  for (int i = tid; i < N_*19; i += 512) {
    int j = i / 19, t2 = i % 19;
    unsigned u = *(const unsigned*)(vg + (base + j)*D_ + h*HD_ + 2*t2);
    Vt[2*t2][j]     = (ushort)(u & 0xffffu);
    Vt[2*t2 + 1][j] = (ushort)(u >> 16);
  }
  for (int i = tid; i < 38*26; i += 512)
    Vt[i / 26][N_ + i % 26] = 0;
  __syncthreads();

  for (int qt = w; qt < 23; qt += 8) {
    const ushort* qp = qg + (base + 16*qt + cl) * D_ + h*HD_;
    short8 qB0 = ld_g8(qp + 8*gr);
    short8 qB1 = ld_g8(qp + 32 + 8*gr);
    float sum_ = 0.f;
    float4v accO[3];
    accO[0] = (float4v){0,0,0,0};
    accO[1] = (float4v){0,0,0,0};
    accO[2] = (float4v){0,0,0,0};
#pragma unroll 1
    for (int pr = 0; pr < 11; ++pr) {
      int k0 = 32*pr;
      int kr0 = k0 + cl;
      int kr1 = k0 + 16 + cl;
      float4v s0a = (float4v){0,0,0,0}, s1a = (float4v){0,0,0,0};
      {
        short8 a00 = *(const short8*)&Ks[kr0][8*gr];
        short8 a10 = *(const short8*)&Ks[kr1][8*gr];
        __builtin_amdgcn_s_setprio(1);
        s0a = __builtin_amdgcn_mfma_f32_16x16x32_bf16(a00, qB0, s0a, 0, 0, 0);
        s1a = __builtin_amdgcn_mfma_f32_16x16x32_bf16(a10, qB0, s1a, 0, 0, 0);
        short8 a01 = g0 ? *(const short8*)&Ks[kr0][32] : z8;
        short8 a11 = g0 ? *(const short8*)&Ks[kr1][32] : z8;
        s0a = __builtin_amdgcn_mfma_f32_16x16x32_bf16(a01, qB1, s0a, 0, 0, 0);
        s1a = __builtin_amdgcn_mfma_f32_16x16x32_bf16(a11, qB1, s1a, 0, 0, 0);
        __builtin_amdgcn_s_setprio(0);
      }
      float p0[4], p1[4];
#pragma unroll
      for (int r = 0; r < 4; ++r) {
        p0[r] = __builtin_exp2f(fminf(s0a[r]*C2_, 80.f));
        p1[r] = __builtin_exp2f(fminf(s1a[r]*C2_, 80.f));
      }
      sum_ += (p0[0] + p0[1]) + (p0[2] + p0[3])
            + (p1[0] + p1[1]) + (p1[2] + p1[3]);
      unsigned u0 = pk_bf(p0[0], p0[1]);
      unsigned u1 = pk_bf(p0[2], p0[3]);
      unsigned u2 = pk_bf(p1[0], p1[1]);
      unsigned u3 = pk_bf(p1[2], p1[3]);
      int srcA = cl + 16*((2*gr) & 3);
      int srcB = srcA + 16;
      unsigned a0 = __shfl(u0, srcA, 64), b0 = __shfl(u1, srcA, 64);
      unsigned c0 = __shfl(u0, srcB, 64), d0 = __shfl(u1, srcB, 64);
      unsigned a2 = __shfl(u2, srcA, 64), b2 = __shfl(u3, srcA, 64);
      unsigned c2 = __shfl(u2, srcB, 64), d2 = __shfl(u3, srcB, 64);
      bool lo = gr < 2;
      union { unsigned u[4]; short8 v; } pbu;
      pbu.u[0] = lo ? a0 : a2;
      pbu.u[1] = lo ? b0 : b2;
      pbu.u[2] = lo ? c0 : c2;
      pbu.u[3] = lo ? d0 : d2;
      short8 pB = pbu.v;
      __builtin_amdgcn_s_setprio(1);
#pragma unroll
      for (int dt = 0; dt < 3; ++dt) {
        short8 aV = (dt < 2 || cl < 6)
            ? *(const short8*)&Vt[16*dt + cl][k0 + 8*gr] : z8;
        accO[dt] = __builtin_amdgcn_mfma_f32_16x16x32_bf16(aV, pB, accO[dt], 0, 0, 0);
      }
      __builtin_amdgcn_s_setprio(0);
    }
    { /* tail tile: keys 352..357 */
      int k0 = 352;
      int kr0 = k0 + cl; if (kr0 > 359) kr0 = 359;
      float4v s0a = (float4v){0,0,0,0};
      {
        short8 a00 = *(const short8*)&Ks[kr0][8*gr];
        s0a = __builtin_amdgcn_mfma_f32_16x16x32_bf16(a00, qB0, s0a, 0, 0, 0);
        short8 a01 = g0 ? *(const short8*)&Ks[kr0][32] : z8;
        s0a = __builtin_amdgcn_mfma_f32_16x16x32_bf16(a01, qB1, s0a, 0, 0, 0);
      }
      float p0[4];
#pragma unroll
      for (int r = 0; r < 4; ++r) {
        float xv = (4*gr + r < 6) ? s0a[r]*C2_ : -1e30f;
        p0[r] = __builtin_exp2f(fminf(xv, 80.f));
      }
      sum_ += (p0[0] + p0[1]) + (p0[2] + p0[3]);
      unsigned u0 = pk_bf(p0[0], p0[1]);
      unsigned u1 = pk_bf(p0[2], p0[3]);
      int srcA = cl + 16*((2*gr) & 3);
      int srcB = srcA + 16;
      unsigned a0 = __shfl(u0, srcA, 64), b0 = __shfl(u1, srcA, 64);
      unsigned c0 = __shfl(u0, srcB, 64), d0 = __shfl(u1, srcB, 64);
      bool lo = gr < 2;
      union { unsigned u[4]; short8 v; } pbu;
      pbu.u[0] = lo ? a0 : 0u;
      pbu.u[1] = lo ? b0 : 0u;
      pbu.u[2] = lo ? c0 : 0u;
      pbu.u[3] = lo ? d0 : 0u;
      short8 pB = pbu.v;
#pragma unroll
      for (int dt = 0; dt < 3; ++dt) {
        short8 aV = (dt < 2 || cl < 6)
            ? *(const short8*)&Vt[16*dt + cl][k0 + 8*gr] : z8;
        accO[dt] = __builtin_amdgcn_mfma_f32_16x16x32_bf16(aV, pB, accO[dt], 0, 0, 0);
      }
    }
    sum_ += __shfl_xor(sum_, 16, 64);
    sum_ += __shfl_xor(sum_, 32, 64);
    int qi = 16*qt + cl;
    if (qi < N_) {
      float inv = 1.f / sum_;
      bf* ap = a + (base + qi)*D_ + h*HD_;
#pragma unroll
      for (int dt = 0; dt < 2; ++dt) {
        *(unsigned*)(ap + 16*dt + 4*gr)     = pk_bf(accO[dt][0]*inv, accO[dt][1]*inv);
        *(unsigned*)(ap + 16*dt + 4*gr + 2) = pk_bf(accO[dt][2]*inv, accO[dt][3]*inv);
      }
      if (gr == 0) {
        *(unsigned*)(ap + 32) = pk_bf(accO[2][0]*inv, accO[2][1]*inv);
        *(unsigned*)(ap + 34) = pk_bf(accO[2][2]*inv, accO[2][3]*inv);
      } else if (gr == 1) {
        *(unsigned*)(ap + 36) = pk_bf(accO[2][0]*inv, accO[2][1]*inv);
      }
    }
  }
}

/* ------------------------------------------------------------------ */
__global__ __launch_bounds__(256) void k_evtpool(
    const float* __restrict__ marker, const void* __restrict__ doy_mask,
    const float* __restrict__ evt_h, float* __restrict__ evtp) {
  __shared__ int hasF32, hasBig;
  if (threadIdx.x == 0) { hasF32 = 0; hasBig = 0; }
  __syncthreads();
  const unsigned* mw = (const unsigned*)doy_mask;
  for (int w = threadIdx.x; w < 732; w += 256) {
    unsigned u = mw[w];
    if (u == 0x3F800000u) hasF32 = 1;
    else if (u > 1u) hasBig = 1;
  }
  __syncthreads();
  int fmt = hasF32 ? 2 : (hasBig ? 1 : 0);
  int b = blockIdx.x;
  float m3 = marker[((b*L_ + (L_-1))*N_ + 0)*4 + 3];
  int doy = (int)(m3 * 365.f); doy = doy < 0 ? 0 : (doy > 365 ? 365 : doy);
  int j = threadIdx.x;
  float mx = -1e30f;
  for (int kx = 0; kx < 8; ++kx) {
    bool mk;
    if (fmt == 2)      mk = ((const float*)doy_mask)[doy*8 + kx] != 0.f;
    else if (fmt == 1) mk = ((const unsigned char*)doy_mask)[doy*8 + kx] != 0;
    else               mk = ((const int*)doy_mask)[doy*8 + kx] != 0;
    if (mk) mx = fmaxf(mx, evt_h[(b*8 + kx)*256 + j]);
  }
  evtp[b*256 + j] = mx;
}

/* ------------------------------------------------------------------ */
__global__ __launch_bounds__(192) void k_final3(
    const bf* __restrict__ x, const float* __restrict__ wcomb,
    const float* __restrict__ wevtsum, const float* __restrict__ evtp,
    const float* __restrict__ b_mm, const float* __restrict__ b_ts,
    float* __restrict__ out) {
  int id = blockIdx.x; int b = id / N_; int n = id % N_;
  __shared__ float xs[1824];
  __shared__ float part[16][12];
  int tid = threadIdx.x;
  for (int e = tid; e < 912; e += 192) {
    int l = e / 76, du = e % 76;
    unsigned u = *(const unsigned*)((const ushort*)x +
        (((long)(b*L_ + l) * N_ + n) * 152 + 2*du));
    xs[l*152 + 2*du]     = lo_bf(u);
    xs[l*152 + 2*du + 1] = hi_bf(u);
  }
  __syncthreads();
  int g2 = tid / 12, p = tid % 12;
  float acc = 0.f;
  for (int e = g2; e < 1824; e += 16)
    acc += xs[e] * wcomb[e*12 + p];
  part[g2][p] = acc;
  __syncthreads();
  if (tid < 12) {
    float s = b_mm[tid] + b_ts[tid];
    for (int e = 0; e < 256; ++e) s += evtp[b*256 + e] * wevtsum[e*12 + tid];
    for (int gg = 0; gg < 16; ++gg) s += part[gg][tid];
    out[(b*12 + tid) * N_ + n] = s;
  }
}

/* ------------------------------------------------------------------ */
extern "C" void kernel_launch(void* const* d_in, const int* in_sizes, int n_in,
                              void* d_out, int out_size, void* d_ws, size_t ws_size,
                              hipStream_t stream) {
  static const int expect[32] = {
    68736, 274944, 72, 24, 3456, 168, 343680,
    138624, 912, 138624, 912, 138624, 912, 138624, 912,
    233472, 1536, 233472, 912,
    912, 912, 912, 912,
    4195328, 262144, 256,
    58752, 12, 21888, 12,
    2928, 2928 };
  int nb = (out_size + 255)/256;
  if (n_in != 32) {
    k_beacon<<<nb, 256, 0, stream>>>((float*)d_out, out_size, 998.f);
    return;
  }
  for (int i = 0; i < 32; ++i) {
    if (in_sizes[i] != expect[i]) {
      k_beacon<<<nb, 256, 0, stream>>>((float*)d_out, out_size, 1000.f + i);
      return;
    }
  }
  if (out_size != 68736) {
    k_beacon<<<nb, 256, 0, stream>>>((float*)d_out, out_size, 997.f);
    return;
  }

  const float* var_x  = (const float*)d_in[0];
  const float* marker = (const float*)d_in[1];
  const float* W_in   = (const float*)d_in[2];
  const float* b_in   = (const float*)d_in[3];
  const float* tod    = (const float*)d_in[4];
  const float* dow    = (const float*)d_in[5];
  const float* adap   = (const float*)d_in[6];
  const float* Wq = (const float*)d_in[7];  const float* bq = (const float*)d_in[8];
  const float* Wk = (const float*)d_in[9];  const float* bk = (const float*)d_in[10];
  const float* Wv = (const float*)d_in[11]; const float* bv = (const float*)d_in[12];
  const float* Wo = (const float*)d_in[13]; const float* bo = (const float*)d_in[14];
  const float* W1 = (const float*)d_in[15]; const float* b1 = (const float*)d_in[16];
  const float* W2 = (const float*)d_in[17]; const float* b2 = (const float*)d_in[18];
  const float* g1 = (const float*)d_in[19]; const float* be1 = (const float*)d_in[20];
  const float* g2 = (const float*)d_in[21]; const float* be2 = (const float*)d_in[22];
  const float* emb   = (const float*)d_in[23];
  const float* W_evt = (const float*)d_in[24]; const float* b_evt = (const float*)d_in[25];
  const float* W_mm  = (const float*)d_in[26]; const float* b_mm  = (const float*)d_in[27];
  const float* W_ts  = (const float*)d_in[28]; const float* b_ts  = (const float*)d_in[29];
  const int* doyi = (const int*)d_in[30];
  const void* doym = d_in[31];

  const long TD = (long)TOK_ * D_;
  size_t need = (size_t)TD * 2 * 5
              + (size_t)(32768 + 4096 + 3072 + 21888) * 4
              + 2764800
              + 4096;
  if (ws_size < need) {
    k_beacon<<<nb, 256, 0, stream>>>((float*)d_out, out_size, (float)(ws_size >> 20));
    return;
  }

  bf* x = (bf*)d_ws;
  bf* q = x + TD;
  bf* k = q + TD;
  bf* v = k + TD;
  bf* a = v + TD;
  float* evt_h   = (float*)(a + TD);
  float* evtp    = evt_h + 32768;
  float* wevtsum = evtp + 4096;
  float* wcomb   = wevtsum + 3072;
  ushort* wprep  = (ushort*)(wcomb + 21888);

  k_prep<<<PREP_B, 256, 0, stream>>>(
      Wq, Wk, Wv, Wo, W1, W2, (unsigned*)wprep,
      var_x, marker, W_in, b_in, tod, dow, adap, x,
      doyi, emb, W_evt, b_evt, evt_h,
      W_mm, W_ts, wcomb, wevtsum);
  k_evtpool<<<16, 256, 0, stream>>>(marker, doym, evt_h, evtp);
  for (int i = 0; i < 6; ++i) {
    const ushort* pl = wprep + (size_t)i * 230400;
    /* fused QKV projection (64-tok blocks) */
    k_gemm7<152,152,3,64,1,false,false><<<TOK_/64, 512, 0, stream>>>(
        x, pl, bq + i*152, bk + i*152, bv + i*152,
        nullptr, nullptr, nullptr, q, k, v);
    if (i < 3)
      k_attn_t2<<<B_*N_, 256, 0, stream>>>(
          (const ushort*)q, (const ushort*)k, (const ushort*)v, a);
    else
      k_attn_s6<<<B_*L_*4, 512, 0, stream>>>(
          (const ushort*)q, (const ushort*)k, (const ushort*)v, a);
    /* fused Wo+LN1+FFN+LN2: x = LN2( FF(LN1(a@Wo + bo + x)) + h ) */
    k_layer3<<<TOK_/64, 512, 0, stream>>>(
        a, x, pl + 96000, pl + 128000, pl + 179200,
        bo + i*152, b1 + i*256, b2 + i*152,
        g1 + i*152, be1 + i*152, g2 + i*152, be2 + i*152, x);
  }
  k_final3<<<B_*N_, 192, 0, stream>>>(x, wcomb, wevtsum, evtp, b_mm, b_ts,
                                      (float*)d_out);
}

// Round 16
// 988.506 us; speedup vs baseline: 1.0210x; 1.0025x over previous
//
#include <hip/hip_runtime.h>
#include <hip/hip_bf16.h>

using bf = __hip_bfloat16;

#define B_   16
#define L_   12
#define N_   358
#define D_   152
#define TOK_ (B_*L_*N_)   /* 68736 */
#define FF_  256
#define HD_  38
#define SCALE_ 0.16222142113076254f  /* 38^-0.5 */
#define C2_   0.23403921469340696f   /* SCALE_ * log2(e) */

__device__ __forceinline__ float bf2f(bf x) { return __bfloat162float(x); }
__device__ __forceinline__ bf f2bf(float f) { return __float2bfloat16(f); }
__device__ __forceinline__ float lo_bf(unsigned u) { return __uint_as_float(u << 16); }
__device__ __forceinline__ float hi_bf(unsigned u) { return __uint_as_float(u & 0xffff0000u); }
__device__ __forceinline__ unsigned pk_bf(float a, float b) {
  union { bf h; unsigned short u; } A, Bu;
  A.h = f2bf(a); Bu.h = f2bf(b);
  return ((unsigned)Bu.u << 16) | A.u;
}
__device__ __forceinline__ ushort f2bf_u(float f) {
  union { bf h; ushort u; } t; t.h = f2bf(f); return t.u;
}

using short8  = __attribute__((ext_vector_type(8))) short;
using float4v = __attribute__((ext_vector_type(4))) float;

/* async global->LDS, 16B per lane; dst is wave-uniform base (HW adds lane*16) */
__device__ __forceinline__ void gl_lds16(const void* g, void* l) {
  __builtin_amdgcn_global_load_lds(
      (const __attribute__((address_space(1))) void*)g,
      (__attribute__((address_space(3))) void*)l, 16, 0, 0);
}

/* copy SUBCB bytes global->LDS; 8 waves interleave 1024B blocks */
template<int SUBCB>
__device__ __forceinline__ void issue_w8(const char* gsrc, ushort* lds, int w, int lane) {
  constexpr int TB = SUBCB >> 10;
  constexpr int TAIL = SUBCB & 1023;
#pragma unroll
  for (int blk0 = 0; blk0 < TB; blk0 += 8) {
    int blk = blk0 + w;
    if (blk < TB)
      gl_lds16(gsrc + blk*1024 + (size_t)lane*16, (char*)lds + blk*1024);
  }
  if (TAIL) {
    if (w == (TB & 7) && lane < TAIL/16)
      gl_lds16(gsrc + TB*1024 + (size_t)lane*16, (char*)lds + TB*1024);
  }
}

/* per-wave count of gl_lds16 issues done by issue_w8<SUBCB> (wave-uniform) */
template<int SUBCB>
__device__ __forceinline__ int issue_cnt(int w) {
  constexpr int TB = SUBCB >> 10;
  constexpr int TAIL = SUBCB & 1023;
  int n = (TB > 8 && w < TB - 8) ? 2 : 1;
  if (TAIL && w == (TB & 7)) n += 1;
  return n;
}

/* counted-vmcnt wait: keep newest n loads in flight (n in {1,2,3}) */
__device__ __forceinline__ void vm_wait(int n) {
  if (n == 1)      asm volatile("s_waitcnt vmcnt(1)" ::: "memory");
  else if (n == 2) asm volatile("s_waitcnt vmcnt(2)" ::: "memory");
  else             asm volatile("s_waitcnt vmcnt(3)" ::: "memory");
}

/* 16B logical load from a 4B-aligned (not necessarily 16B-aligned) address */
__device__ __forceinline__ short8 ld_g8(const ushort* p) {
  union { unsigned u[4]; short8 v; } t;
  t.u[0] = *(const unsigned*)(p);
  t.u[1] = *(const unsigned*)(p + 2);
  t.u[2] = *(const unsigned*)(p + 4);
  t.u[3] = *(const unsigned*)(p + 6);
  return t.v;
}

/* ------------------------------------------------------------------ */
__global__ void k_beacon(float* out, int n, float val) {
  int i = blockIdx.x * 256 + threadIdx.x;
  if (i < n) out[i] = val;
}

/* ================= fused prep: wprep | embed | evt1 | wcomb =======
   wprep: 4 output words per thread (jj-unrolled) -> 4x memory-level
   parallelism in the latency-bound strided-read region. Per-index
   body identical to the proven decoder.                              */
#define WPREP_B 675      /* ceil(691200 / 1024) */
#define EMB_B   269
#define EVT_B   128
#define WC_B    86
#define PREP_B  (WPREP_B + EMB_B + EVT_B + WC_B)   /* 1158 */

__device__ void d_wprep(int bid, int tid,
    const float* __restrict__ Wq, const float* __restrict__ Wk,
    const float* __restrict__ Wv, const float* __restrict__ Wo,
    const float* __restrict__ W1, const float* __restrict__ W2,
    unsigned* __restrict__ out) {
#pragma unroll
  for (int jj = 0; jj < 4; ++jj) {
    int i = bid * 1024 + jj * 256 + tid;
    if (i >= 6*115200) continue;
    int layer = i / 115200, r = i % 115200;
    const float* src; int K, Nd, d, up, c;
    if (r < 48000) {
      c = r / 9600; int rr = r % 9600; int m = rr / 3200; int r2 = rr % 3200;
      d = r2 / 20; up = r2 % 20;
      src = (m == 0 ? Wq : (m == 1 ? Wk : Wv)) + layer*23104; K = 152; Nd = 152;
    } else if (r < 64000) {
      int rr = r - 48000; c = rr / 3200; int r2 = rr % 3200;
      d = r2 / 20; up = r2 % 20;
      src = Wo + layer*23104; K = 152; Nd = 152;
    } else if (r < 89600) {
      int rr = r - 64000; c = rr / 5120; int r2 = rr % 5120;
      d = r2 / 20; up = r2 % 20;
      src = W1 + layer*38912; K = 152; Nd = 256;
    } else {
      int rr = r - 89600; c = rr / 3200; int r2 = rr % 3200;
      d = r2 / 20; up = r2 % 20;
      src = W2 + layer*38912; K = 256; Nd = 152;
    }
    float v0 = 0.f, v1 = 0.f;
    int k0 = 32*c + 2*up;
    if (up < 16 && d < Nd) {
      if (k0 < K)     v0 = src[(long)k0*Nd + d];
      if (k0 + 1 < K) v1 = src[(long)(k0+1)*Nd + d];
    }
    out[i] = pk_bf(v0, v1);
  }
}

__device__ void d_embed(int bid, int tid,
    const float* __restrict__ var_x, const float* __restrict__ marker,
    const float* __restrict__ W_in, const float* __restrict__ b_in,
    const float* __restrict__ tod_emb, const float* __restrict__ dow_emb,
    const float* __restrict__ adap, bf* __restrict__ x) {
  int t = bid * 256 + tid;
  if (t >= TOK_) return;
  int n = t % N_;
  int l = (t / N_) % L_;
  float var = var_x[t];
  float m0 = marker[t*4 + 0];
  float m1 = marker[t*4 + 1];
  int tod = (int)(m0 * 144.f); tod = tod < 0 ? 0 : (tod > 143 ? 143 : tod);
  int dw  = (int)(m1 * 7.f);   dw  = dw  < 0 ? 0 : (dw  > 6   ? 6   : dw);
  bf* xp = x + (long)t * D_;
  for (int d = 0; d < 24; ++d)
    xp[d] = f2bf(var * W_in[d] + m0 * W_in[24 + d] + m1 * W_in[48 + d] + b_in[d]);
  for (int d = 0; d < 24; ++d) xp[24 + d] = f2bf(tod_emb[tod*24 + d]);
  for (int d = 0; d < 24; ++d) xp[48 + d] = f2bf(dow_emb[dw*24 + d]);
  for (int d = 0; d < 80; ++d) xp[72 + d] = f2bf(adap[(l*N_ + n)*80 + d]);
}

__device__ void d_evt1(int bk, int tid,
    const float* __restrict__ marker, const int* __restrict__ doy_idx,
    const float* __restrict__ emb, const float* __restrict__ W_evt,
    const float* __restrict__ b_evt, float* __restrict__ evt_h) {
  int b = bk >> 3; int ks = bk & 7;
  float m3 = marker[((b*L_ + (L_-1))*N_ + 0)*4 + 3];
  int doy = (int)(m3 * 365.f); doy = doy < 0 ? 0 : (doy > 365 ? 365 : doy);
  int idx = doy_idx[doy*8 + ks];
  if (idx < 0 || idx > 4096) idx = 0;
  int d = tid;
  float acc = b_evt[d];
  const float* er = emb + (long)idx * 1024;
  for (int e = 0; e < 1024; ++e)
    acc += er[e] * W_evt[e*256 + d];
  evt_h[bk*256 + d] = acc;
}

__device__ void d_wcomb(int bid, int tid,
    const float* __restrict__ W_mm, const float* __restrict__ W_ts,
    float* __restrict__ wcomb, float* __restrict__ wevtsum) {
  int i = bid * 256 + tid;
  if (i < 1824*12) {
    int r = i / 12, p = i % 12, l = r / 152, d = r % 152;
    wcomb[i] = W_mm[(l*408 + 256 + d)*12 + p] + W_ts[i];
  }
  if (i < 256*12) {
    int e = i / 12, p = i % 12;
    float s = 0.f;
    for (int l = 0; l < 12; ++l) s += W_mm[(l*408 + e)*12 + p];
    wevtsum[i] = s;
  }
}

__global__ __launch_bounds__(256) void k_prep(
    const float* Wq, const float* Wk, const float* Wv, const float* Wo,
    const float* W1, const float* W2, unsigned* wout,
    const float* var_x, const float* marker, const float* W_in,
    const float* b_in, const float* tod_emb, const float* dow_emb,
    const float* adap, bf* x,
    const int* doyi, const float* emb, const float* W_evt,
    const float* b_evt, float* evt_h,
    const float* W_mm, const float* W_ts, float* wcomb, float* wevtsum) {
  int bid = blockIdx.x, tid = threadIdx.x;
  if (bid < WPREP_B)
    d_wprep(bid, tid, Wq, Wk, Wv, Wo, W1, W2, wout);
  else if (bid < WPREP_B + EMB_B)
    d_embed(bid - WPREP_B, tid, var_x, marker, W_in, b_in, tod_emb, dow_emb, adap, x);
  else if (bid < WPREP_B + EMB_B + EVT_B)
    d_evt1(bid - WPREP_B - EMB_B, tid, marker, doyi, emb, W_evt, b_evt, evt_h);
  else
    d_wcomb(bid - WPREP_B - EMB_B - EVT_B, tid, W_mm, W_ts, wcomb, wevtsum);
}

/* ------------------------------------------------------------------ */
/* GEMM v8 (round-7/9 proven): counted-vmcnt two-barrier K-loop.
   Used only for the fused QKV projection.                            */
template<int K, int Nd, int NW, int TOKB, int CSPLIT, bool RELU, bool LN>
__global__ __launch_bounds__(512) void k_gemm7(
    const bf* __restrict__ X, const ushort* __restrict__ Wg,
    const float* __restrict__ bi0, const float* __restrict__ bi1,
    const float* __restrict__ bi2, const bf* __restrict__ Res,
    const float* __restrict__ g, const float* __restrict__ bb,
    bf* __restrict__ Y0, bf* __restrict__ Y1, bf* __restrict__ Y2) {
  constexpr int NJ   = (Nd + 15) / 16;
  constexpr int NdP  = NJ * 16;
  constexpr int KC   = (K + 31) / 32;
  constexpr int G    = NW * CSPLIT;
  constexpr int S    = KC * G;
  constexpr int IR   = NdP / CSPLIT;
  constexpr int SUB_USH = IR * 40;
  constexpr int SUBCB   = SUB_USH * 2;
  constexpr int NJW  = IR / 32;
  constexpr int MR   = TOKB / 64;
  constexpr bool GLX = (K == 152);
  constexpr int XSTR = GLX ? K : (K + 8);
  __shared__ __align__(16) ushort Xs[TOKB * XSTR + 8];
  __shared__ __align__(16) ushort Wb[2 * SUB_USH];
  long row0 = (long)blockIdx.x * TOKB;
  int tid = threadIdx.x;
  int lane = tid & 63, w = tid >> 6;
  int cl = lane & 15, gr = lane >> 4;
  int wr = w >> 1, wc = w & 1;
  if constexpr (GLX) {
    constexpr int TBX = TOKB * K * 2 / 1024;
    const char* Xgc = (const char*)(X + row0 * K);
#pragma unroll
    for (int b0 = 0; b0 < TBX; b0 += 8) {
      int blk = b0 + w;
      if (blk < TBX)
        gl_lds16(Xgc + blk*1024 + (size_t)lane*16, (char*)Xs + blk*1024);
    }
  } else {
    const char* Xgc = (const char*)(X + row0 * K);
    for (int i = tid; i < TOKB*(K/8); i += 512) {
      int r = i / (K/8), c = i % (K/8);
      *(short8*)&Xs[r*XSTR + 8*c] = *(const short8*)(Xgc + r*(K*2) + c*16);
    }
    __syncthreads();
  }
  const char* gW = (const char*)Wg;
  issue_w8<SUBCB>(gW, Wb, w, lane);
  const int nw = issue_cnt<SUBCB>(w);
  float4v acc[G][MR][NJW];
#pragma unroll
  for (int gi = 0; gi < G; ++gi)
#pragma unroll
    for (int mi = 0; mi < MR; ++mi)
#pragma unroll
      for (int j = 0; j < NJW; ++j) acc[gi][mi][j] = (float4v){0.f,0.f,0.f,0.f};
#pragma unroll
  for (int s = 0; s < S; ++s) {
    if (s + 1 < S) {
      issue_w8<SUBCB>(gW + (size_t)(s+1)*SUBCB, Wb + ((s+1)&1)*SUB_USH, w, lane);
      vm_wait(nw);
    } else {
      asm volatile("s_waitcnt vmcnt(0)" ::: "memory");
    }
    __builtin_amdgcn_s_barrier();
    int kc = (s / G) * 32;
    const ushort* wb = Wb + (s&1)*SUB_USH;
    short8 af[MR];
#pragma unroll
    for (int mi = 0; mi < MR; ++mi)
      af[mi] = *(const short8*)&Xs[((TOKB/4)*wr + 16*mi + cl)*XSTR + kc + 8*gr];
#pragma unroll
    for (int j = 0; j < NJW; ++j) {
      short8 bv = *(const short8*)&wb[((IR/2)*wc + 16*j + cl)*40 + 8*gr];
#pragma unroll
      for (int mi = 0; mi < MR; ++mi)
        acc[s % G][mi][j] =
            __builtin_amdgcn_mfma_f32_16x16x32_bf16(af[mi], bv, acc[s % G][mi][j], 0, 0, 0);
    }
    asm volatile("s_waitcnt lgkmcnt(0)" ::: "memory");
    __builtin_amdgcn_s_barrier();
  }
  if constexpr (!LN) {
#pragma unroll
    for (int gi = 0; gi < G; ++gi) {
      bf* Y = (NW > 1) ? (gi == 0 ? Y0 : (gi == 1 ? Y1 : Y2)) : Y0;
      const float* bp = (NW > 1) ? (gi == 0 ? bi0 : (gi == 1 ? bi1 : bi2)) : bi0;
      int colb = (CSPLIT > 1 ? IR*gi : 0) + (IR/2)*wc;
#pragma unroll
      for (int j = 0; j < NJW; ++j) {
        int col = colb + 16*j + cl;
        if (col < Nd) {
          float bvs = bp[col];
#pragma unroll
          for (int mi = 0; mi < MR; ++mi) {
            long rw = row0 + (TOKB/4)*wr + 16*mi + 4*gr;
#pragma unroll
            for (int r = 0; r < 4; ++r) {
              float val = acc[gi][mi][j][r] + bvs;
              if (RELU) val = fmaxf(val, 0.f);
              Y[(rw + r) * Nd + col] = f2bf(val);
            }
          }
        }
      }
    }
  } else {
    float* LNb = (float*)Wb;
    int colb = (IR/2)*wc;
#pragma unroll
    for (int j = 0; j < NJW; ++j) {
      int col = colb + 16*j + cl;
      if (col < Nd) {
        float bvs = bi0[col];
#pragma unroll
        for (int mi = 0; mi < MR; ++mi) {
          long rw = row0 + (TOKB/4)*wr + 16*mi + 4*gr;
#pragma unroll
          for (int r = 0; r < 4; ++r)
            acc[0][mi][j][r] += bvs + bf2f(Res[(rw + r) * Nd + col]);
        }
      }
    }
    float mean[MR][4], rs[MR][4];
#pragma unroll
    for (int mi = 0; mi < MR; ++mi)
#pragma unroll
      for (int r = 0; r < 4; ++r) {
        float s = 0.f;
#pragma unroll
        for (int j = 0; j < NJW; ++j) s += acc[0][mi][j][r];
        s += __shfl_xor(s, 1, 64); s += __shfl_xor(s, 2, 64);
        s += __shfl_xor(s, 4, 64); s += __shfl_xor(s, 8, 64);
        if (cl == 0) LNb[((wr*MR + mi)*2 + wc)*16 + 4*gr + r] = s;
      }
    __syncthreads();
#pragma unroll
    for (int mi = 0; mi < MR; ++mi)
#pragma unroll
      for (int r = 0; r < 4; ++r) {
        float tot = LNb[((wr*MR + mi)*2 + 0)*16 + 4*gr + r]
                  + LNb[((wr*MR + mi)*2 + 1)*16 + 4*gr + r];
        mean[mi][r] = tot * (1.f / (float)Nd);
      }
#pragma unroll
    for (int mi = 0; mi < MR; ++mi)
#pragma unroll
      for (int r = 0; r < 4; ++r) {
        float s2 = 0.f;
#pragma unroll
        for (int j = 0; j < NJW; ++j) {
          int col = colb + 16*j + cl;
          if (col < Nd) {
            float dv = acc[0][mi][j][r] - mean[mi][r];
            s2 += dv*dv;
          }
        }
        s2 += __shfl_xor(s2, 1, 64); s2 += __shfl_xor(s2, 2, 64);
        s2 += __shfl_xor(s2, 4, 64); s2 += __shfl_xor(s2, 8, 64);
        if (cl == 0) LNb[256 + ((wr*MR + mi)*2 + wc)*16 + 4*gr + r] = s2;
      }
    __syncthreads();
#pragma unroll
    for (int mi = 0; mi < MR; ++mi)
#pragma unroll
      for (int r = 0; r < 4; ++r) {
        float tot2 = LNb[256 + ((wr*MR + mi)*2 + 0)*16 + 4*gr + r]
                   + LNb[256 + ((wr*MR + mi)*2 + 1)*16 + 4*gr + r];
        rs[mi][r] = rsqrtf(tot2 * (1.f / (float)Nd) + 1e-5f);
      }
#pragma unroll
    for (int j = 0; j < NJW; ++j) {
      int col = colb + 16*j + cl;
      if (col < Nd) {
        float gv = g[col], bv2 = bb[col];
#pragma unroll
        for (int mi = 0; mi < MR; ++mi) {
          long rw = row0 + (TOKB/4)*wr + 16*mi + 4*gr;
#pragma unroll
          for (int r = 0; r < 4; ++r)
            Y0[(rw + r) * Nd + col] =
                f2bf((acc[0][mi][j][r] - mean[mi][r]) * rs[mi][r] * gv + bv2);
        }
      }
    }
  }
}

/* ------------------------------------------------------------------ */
/* k_layer3 (round-11 proven): fused Wo+LN1+FF1+ReLU+FF2+LN2.
   ALL sync = __syncthreads() (full per-wave vmcnt+lgkmcnt drain).    */
__global__ __launch_bounds__(512) void k_layer3(
    const bf* __restrict__ A, const bf* __restrict__ Xres,
    const ushort* __restrict__ Wog, const ushort* __restrict__ W1g,
    const ushort* __restrict__ W2g,
    const float* __restrict__ bo, const float* __restrict__ b1,
    const float* __restrict__ b2,
    const float* __restrict__ g1v, const float* __restrict__ be1,
    const float* __restrict__ g2v, const float* __restrict__ be2,
    bf* __restrict__ Y) {
  constexpr int S0 = 5,  SUB0 = 6400;
  constexpr int S1 = 10, SUB1 = 5120;
  constexpr int S2 = 8,  SUB2 = 6400;
  constexpr int HSTR = 260;
  __shared__ __align__(16) ushort S_[29440];
  ushort* Xs  = S_;
  ushort* W0b = S_ + 9728;
  ushort* W1b = S_ + 9728;
  ushort* Hs2 = S_;
  ushort* W2b = S_ + 16640;
  float*  LNb1 = (float*)(S_ + 22528);
  long row0 = (long)blockIdx.x * 64;
  int tid = threadIdx.x, lane = tid & 63, w = tid >> 6;
  int cl = lane & 15, gr = lane >> 4;
  int wr = w >> 1, wc = w & 1;
  int colb = 80*wc;
  {
    const char* Agc = (const char*)(A + row0 * 152);
#pragma unroll
    for (int b0 = 0; b0 < 19; b0 += 8) {
      int blk = b0 + w;
      if (blk < 19)
        gl_lds16(Agc + blk*1024 + (size_t)lane*16, (char*)Xs + blk*1024);
    }
  }
  issue_w8<SUB0*2>((const char*)Wog, W0b, w, lane);
  __syncthreads();
  float4v acc0[5];
#pragma unroll
  for (int j = 0; j < 5; ++j) acc0[j] = (float4v){0.f,0.f,0.f,0.f};
#pragma unroll
  for (int s = 0; s < S0; ++s) {
    if (s + 1 < S0)
      issue_w8<SUB0*2>((const char*)Wog + (size_t)(s+1)*SUB0*2,
                       W0b + ((s+1)&1)*SUB0, w, lane);
    int kc = s * 32;
    const ushort* wb = W0b + (s&1)*SUB0;
    short8 af = *(const short8*)&Xs[(16*wr + cl)*152 + kc + 8*gr];
#pragma unroll
    for (int j = 0; j < 5; ++j) {
      short8 bv = *(const short8*)&wb[(80*wc + 16*j + cl)*40 + 8*gr];
      acc0[j] =
          __builtin_amdgcn_mfma_f32_16x16x32_bf16(af, bv, acc0[j], 0, 0, 0);
    }
    __syncthreads();
  }
#pragma unroll
  for (int j = 0; j < 5; ++j) {
    int col = colb + 16*j + cl;
    if (col < D_) {
      float bvs = bo[col];
#pragma unroll
      for (int r = 0; r < 4; ++r)
        acc0[j][r] += bvs + bf2f(Xres[(row0 + 16*wr + 4*gr + r) * D_ + col]);
    }
  }
  float mean1[4], rsv1[4];
#pragma unroll
  for (int r = 0; r < 4; ++r) {
    float s = 0.f;
#pragma unroll
    for (int j = 0; j < 5; ++j)
      if (colb + 16*j + cl < D_) s += acc0[j][r];
    s += __shfl_xor(s, 1, 64); s += __shfl_xor(s, 2, 64);
    s += __shfl_xor(s, 4, 64); s += __shfl_xor(s, 8, 64);
    if (cl == 0) LNb1[(wr*2 + wc)*16 + 4*gr + r] = s;
  }
  __syncthreads();
#pragma unroll
  for (int r = 0; r < 4; ++r) {
    float tot = LNb1[(wr*2 + 0)*16 + 4*gr + r] + LNb1[(wr*2 + 1)*16 + 4*gr + r];
    mean1[r] = tot * (1.f / (float)D_);
  }
#pragma unroll
  for (int r = 0; r < 4; ++r) {
    float s2 = 0.f;
#pragma unroll
    for (int j = 0; j < 5; ++j) {
      int col = colb + 16*j + cl;
      if (col < D_) { float dv = acc0[j][r] - mean1[r]; s2 += dv*dv; }
    }
    s2 += __shfl_xor(s2, 1, 64); s2 += __shfl_xor(s2, 2, 64);
    s2 += __shfl_xor(s2, 4, 64); s2 += __shfl_xor(s2, 8, 64);
    if (cl == 0) LNb1[128 + (wr*2 + wc)*16 + 4*gr + r] = s2;
  }
  __syncthreads();
#pragma unroll
  for (int r = 0; r < 4; ++r) {
    float tot2 = LNb1[128 + (wr*2 + 0)*16 + 4*gr + r]
               + LNb1[128 + (wr*2 + 1)*16 + 4*gr + r];
    rsv1[r] = rsqrtf(tot2 * (1.f / (float)D_) + 1e-5f);
  }
  unsigned hres[5][2];
#pragma unroll
  for (int j = 0; j < 5; ++j) {
    int col = colb + 16*j + cl;
    if (col < D_) {
      float gv = g1v[col], bv2 = be1[col];
      ushort u[4];
#pragma unroll
      for (int r = 0; r < 4; ++r) {
        u[r] = f2bf_u((acc0[j][r] - mean1[r]) * rsv1[r] * gv + bv2);
        Xs[(16*wr + 4*gr + r)*152 + col] = u[r];
      }
      hres[j][0] = (unsigned)u[0] | ((unsigned)u[1] << 16);
      hres[j][1] = (unsigned)u[2] | ((unsigned)u[3] << 16);
    } else {
      hres[j][0] = 0u; hres[j][1] = 0u;
    }
  }
  issue_w8<SUB1*2>((const char*)W1g, W1b, w, lane);
  __syncthreads();
  float4v acc1[2][4];
#pragma unroll
  for (int g2 = 0; g2 < 2; ++g2)
#pragma unroll
    for (int j = 0; j < 4; ++j) acc1[g2][j] = (float4v){0.f,0.f,0.f,0.f};
#pragma unroll
  for (int s = 0; s < S1; ++s) {
    if (s + 1 < S1)
      issue_w8<SUB1*2>((const char*)W1g + (size_t)(s+1)*SUB1*2,
                       W1b + ((s+1)&1)*SUB1, w, lane);
    int kc = (s / 2) * 32;
    const ushort* wb = W1b + (s&1)*SUB1;
    short8 af = *(const short8*)&Xs[(16*wr + cl)*152 + kc + 8*gr];
#pragma unroll
    for (int j = 0; j < 4; ++j) {
      short8 bv = *(const short8*)&wb[(64*wc + 16*j + cl)*40 + 8*gr];
      acc1[s&1][j] =
          __builtin_amdgcn_mfma_f32_16x16x32_bf16(af, bv, acc1[s&1][j], 0, 0, 0);
    }
    __syncthreads();
  }
#pragma unroll
  for (int g2 = 0; g2 < 2; ++g2)
#pragma unroll
    for (int j = 0; j < 4; ++j) {
      int col = g2*128 + 64*wc + 16*j + cl;
      float bvs = b1[col];
#pragma unroll
      for (int r = 0; r < 4; ++r) {
        int row = 16*wr + 4*gr + r;
        Hs2[row*HSTR + col] = f2bf_u(fmaxf(acc1[g2][j][r] + bvs, 0.f));
      }
    }
  issue_w8<SUB2*2>((const char*)W2g, W2b, w, lane);
  __syncthreads();
  float4v acc2[5];
#pragma unroll
  for (int j = 0; j < 5; ++j) acc2[j] = (float4v){0.f,0.f,0.f,0.f};
#pragma unroll
  for (int s = 0; s < S2; ++s) {
    if (s + 1 < S2)
      issue_w8<SUB2*2>((const char*)W2g + (size_t)(s+1)*SUB2*2,
                       W2b + ((s+1)&1)*SUB2, w, lane);
    int kc = s * 32;
    const ushort* wb = W2b + (s&1)*SUB2;
    short8 af = *(const short8*)&Hs2[(16*wr + cl)*HSTR + kc + 8*gr];
#pragma unroll
    for (int j = 0; j < 5; ++j) {
      short8 bv = *(const short8*)&wb[(80*wc + 16*j + cl)*40 + 8*gr];
      acc2[j] =
          __builtin_amdgcn_mfma_f32_16x16x32_bf16(af, bv, acc2[j], 0, 0, 0);
    }
    __syncthreads();
  }
  float* LNb = (float*)W2b;
#pragma unroll
  for (int j = 0; j < 5; ++j) {
    int col = colb + 16*j + cl;
    if (col < D_) {
      float bvs = b2[col];
#pragma unroll
      for (int r = 0; r < 4; ++r)
        acc2[j][r] += bvs + ((r & 1) ? hi_bf(hres[j][r>>1]) : lo_bf(hres[j][r>>1]));
    }
  }
  float mean[4], rsv[4];
#pragma unroll
  for (int r = 0; r < 4; ++r) {
    float s = 0.f;
#pragma unroll
    for (int j = 0; j < 5; ++j)
      if (colb + 16*j + cl < D_) s += acc2[j][r];
    s += __shfl_xor(s, 1, 64); s += __shfl_xor(s, 2, 64);
    s += __shfl_xor(s, 4, 64); s += __shfl_xor(s, 8, 64);
    if (cl == 0) LNb[(wr*2 + wc)*16 + 4*gr + r] = s;
  }
  __syncthreads();
#pragma unroll
  for (int r = 0; r < 4; ++r) {
    float tot = LNb[(wr*2 + 0)*16 + 4*gr + r] + LNb[(wr*2 + 1)*16 + 4*gr + r];
    mean[r] = tot * (1.f / (float)D_);
  }
#pragma unroll
  for (int r = 0; r < 4; ++r) {
    float s2 = 0.f;
#pragma unroll
    for (int j = 0; j < 5; ++j) {
      int col = colb + 16*j + cl;
      if (col < D_) { float dv = acc2[j][r] - mean[r]; s2 += dv*dv; }
    }
    s2 += __shfl_xor(s2, 1, 64); s2 += __shfl_xor(s2, 2, 64);
    s2 += __shfl_xor(s2, 4, 64); s2 += __shfl_xor(s2, 8, 64);
    if (cl == 0) LNb[128 + (wr*2 + wc)*16 + 4*gr + r] = s2;
  }
  __syncthreads();
#pragma unroll
  for (int r = 0; r < 4; ++r) {
    float tot2 = LNb[128 + (wr*2 + 0)*16 + 4*gr + r]
               + LNb[128 + (wr*2 + 1)*16 + 4*gr + r];
    rsv[r] = rsqrtf(tot2 * (1.f / (float)D_) + 1e-5f);
  }
#pragma unroll
  for (int j = 0; j < 5; ++j) {
    int col = colb + 16*j + cl;
    if (col < D_) {
      float gv = g2v[col], bv2 = be2[col];
#pragma unroll
      for (int r = 0; r < 4; ++r)
        Y[(row0 + 16*wr + 4*gr + r) * D_ + col] =
            f2bf((acc2[j][r] - mean[r]) * rsv[r] * gv + bv2);
    }
  }
}

/* ------------------------------------------------------------------ */
/* Temporal attention v2 (round-5 proven): MFMA swapped-operand.      */
__global__ __launch_bounds__(256) void k_attn_t2(
    const ushort* __restrict__ qg, const ushort* __restrict__ kg,
    const ushort* __restrict__ vg, bf* __restrict__ a) {
  int id = blockIdx.x; int b = id / N_; int n = id % N_;
  __shared__ ushort Ksh[4][16][40];
  __shared__ ushort Qsh[4][16][40];
  __shared__ ushort Vth[4][40][16];
  int tid = threadIdx.x;
  for (int i = tid; i < 1280; i += 256) {
    ((unsigned*)Ksh)[i] = 0u; ((unsigned*)Qsh)[i] = 0u; ((unsigned*)Vth)[i] = 0u;
  }
  __syncthreads();
  for (int i = tid; i < 4*12*19; i += 256) {
    int h = i / 228, r = i % 228, l = r / 19, t2 = r % 19;
    long off = ((long)(b*L_ + l) * N_ + n) * D_ + h*HD_ + 2*t2;
    *(unsigned*)&Ksh[h][l][2*t2] = *(const unsigned*)(kg + off);
    *(unsigned*)&Qsh[h][l][2*t2] = *(const unsigned*)(qg + off);
  }
  for (int i = tid; i < 4*12*19; i += 256) {
    int h = i / 228, r = i % 228, l = r / 19, t2 = r % 19;
    long off = ((long)(b*L_ + l) * N_ + n) * D_ + h*HD_ + 2*t2;
    unsigned u = *(const unsigned*)(vg + off);
    Vth[h][2*t2][l]     = (ushort)(u & 0xffffu);
    Vth[h][2*t2 + 1][l] = (ushort)(u >> 16);
  }
  __syncthreads();
  int lane = tid & 63, w = tid >> 6;
  int cl = lane & 15, gr = lane >> 4;
  const short8 z8 = {0,0,0,0,0,0,0,0};
  short8 a00 = *(const short8*)&Ksh[w][cl][8*gr];
  short8 qB0 = *(const short8*)&Qsh[w][cl][8*gr];
  short8 a01 = (gr == 0) ? *(const short8*)&Ksh[w][cl][32] : z8;
  short8 qB1 = (gr == 0) ? *(const short8*)&Qsh[w][cl][32] : z8;
  float4v sa = (float4v){0,0,0,0};
  sa = __builtin_amdgcn_mfma_f32_16x16x32_bf16(a00, qB0, sa, 0, 0, 0);
  sa = __builtin_amdgcn_mfma_f32_16x16x32_bf16(a01, qB1, sa, 0, 0, 0);
  float p[4];
#pragma unroll
  for (int r = 0; r < 4; ++r) {
    float xv = (4*gr + r < 12) ? sa[r]*C2_ : -1e30f;
    p[r] = __builtin_exp2f(fminf(xv, 80.f));
  }
  float sum_ = (p[0] + p[1]) + (p[2] + p[3]);
  sum_ += __shfl_xor(sum_, 16, 64);
  sum_ += __shfl_xor(sum_, 32, 64);
  unsigned u0 = pk_bf(p[0], p[1]);
  unsigned u1 = pk_bf(p[2], p[3]);
  int srcA = cl + 32*(gr & 1);
  int srcB = srcA + 16;
  unsigned w0 = __shfl(u0, srcA, 64), w1 = __shfl(u1, srcA, 64);
  unsigned w2 = __shfl(u0, srcB, 64), w3 = __shfl(u1, srcB, 64);
  union { unsigned u[4]; short8 v; } pbu;
  bool gv = gr < 2;
  pbu.u[0] = gv ? w0 : 0u; pbu.u[1] = gv ? w1 : 0u;
  pbu.u[2] = gv ? w2 : 0u; pbu.u[3] = gv ? w3 : 0u;
  short8 pB = pbu.v;
  float4v accO[3];
#pragma unroll
  for (int dt = 0; dt < 3; ++dt) {
    short8 aV = (gv && (dt < 2 || cl < 8))
        ? *(const short8*)&Vth[w][16*dt + cl][8*gr] : z8;
    accO[dt] = (float4v){0,0,0,0};
    accO[dt] = __builtin_amdgcn_mfma_f32_16x16x32_bf16(aV, pB, accO[dt], 0, 0, 0);
  }
  if (cl < 12) {
    float inv = 1.f / sum_;
    bf* ap = a + ((long)(b*L_ + cl) * N_ + n) * D_ + w*HD_;
#pragma unroll
    for (int dt = 0; dt < 2; ++dt) {
      *(unsigned*)(ap + 16*dt + 4*gr)     = pk_bf(accO[dt][0]*inv, accO[dt][1]*inv);
      *(unsigned*)(ap + 16*dt + 4*gr + 2) = pk_bf(accO[dt][2]*inv, accO[dt][3]*inv);
    }
    if (gr == 0) {
      *(unsigned*)(ap + 32) = pk_bf(accO[2][0]*inv, accO[2][1]*inv);
      *(unsigned*)(ap + 34) = pk_bf(accO[2][2]*inv, accO[2][3]*inv);
    } else if (gr == 1) {
      *(unsigned*)(ap + 36) = pk_bf(accO[2][0]*inv, accO[2][1]*inv);
    }
  }
}

/* ------------------------------------------------------------------ */
/* Spatial attention v6b (round-9 proven): one (b,l,h) unit per block. */
__global__ __launch_bounds__(512) void k_attn_s6(
    const ushort* __restrict__ qg, const ushort* __restrict__ kg,
    const ushort* __restrict__ vg, bf* __restrict__ a) {
  __shared__ ushort Ks[360][40];
  __shared__ ushort Vt[38][392];
  int tid = threadIdx.x;
  int lane = tid & 63, w = tid >> 6;
  int cl = lane & 15, gr = lane >> 4;
  bool g0 = (gr == 0);
  const short8 z8 = {0,0,0,0,0,0,0,0};

  int id = blockIdx.x;
  int h = id & 3; int s = id >> 2;
  int b = s / L_; int l = s % L_;
  long base = (long)(b*L_ + l) * N_;
  for (int i = tid; i < 360*20; i += 512) {
    int j = i / 20, t2 = i % 20;
    unsigned u = 0u;
    if (j < N_ && t2 < 19)
      u = *(const unsigned*)(kg + (base + j)*D_ + h*HD_ + 2*t2);
    *(unsigned*)&Ks[j][2*t2] = u;
  }
  for (int i = tid; i < N_*19; i += 512) {
    int j = i / 19, t2 = i % 19;
    unsigned u = *(const unsigned*)(vg + (base + j)*D_ + h*HD_ + 2*t2);
    Vt[2*t2][j]     = (ushort)(u & 0xffffu);
    Vt[2*t2 + 1][j] = (ushort)(u >> 16);
  }
  for (int i = tid; i < 38*26; i += 512)
    Vt[i / 26][N_ + i % 26] = 0;
  __syncthreads();

  for (int qt = w; qt < 23; qt += 8) {
    const ushort* qp = qg + (base + 16*qt + cl) * D_ + h*HD_;
    short8 qB0 = ld_g8(qp + 8*gr);
    short8 qB1 = ld_g8(qp + 32 + 8*gr);
    float sum_ = 0.f;
    float4v accO[3];
    accO[0] = (float4v){0,0,0,0};
    accO[1] = (float4v){0,0,0,0};
    accO[2] = (float4v){0,0,0,0};
#pragma unroll 1
    for (int pr = 0; pr < 11; ++pr) {
      int k0 = 32*pr;
      int kr0 = k0 + cl;
      int kr1 = k0 + 16 + cl;
      float4v s0a = (float4v){0,0,0,0}, s1a = (float4v){0,0,0,0};
      {
        short8 a00 = *(const short8*)&Ks[kr0][8*gr];
        short8 a10 = *(const short8*)&Ks[kr1][8*gr];
        __builtin_amdgcn_s_setprio(1);
        s0a = __builtin_amdgcn_mfma_f32_16x16x32_bf16(a00, qB0, s0a, 0, 0, 0);
        s1a = __builtin_amdgcn_mfma_f32_16x16x32_bf16(a10, qB0, s1a, 0, 0, 0);
        short8 a01 = g0 ? *(const short8*)&Ks[kr0][32] : z8;
        short8 a11 = g0 ? *(const short8*)&Ks[kr1][32] : z8;
        s0a = __builtin_amdgcn_mfma_f32_16x16x32_bf16(a01, qB1, s0a, 0, 0, 0);
        s1a = __builtin_amdgcn_mfma_f32_16x16x32_bf16(a11, qB1, s1a, 0, 0, 0);
        __builtin_amdgcn_s_setprio(0);
      }
      float p0[4], p1[4];
#pragma unroll
      for (int r = 0; r < 4; ++r) {
        p0[r] = __builtin_exp2f(fminf(s0a[r]*C2_, 80.f));
        p1[r] = __builtin_exp2f(fminf(s1a[r]*C2_, 80.f));
      }
      sum_ += (p0[0] + p0[1]) + (p0[2] + p0[3])
            + (p1[0] + p1[1]) + (p1[2] + p1[3]);
      unsigned u0 = pk_bf(p0[0], p0[1]);
      unsigned u1 = pk_bf(p0[2], p0[3]);
      unsigned u2 = pk_bf(p1[0], p1[1]);
      unsigned u3 = pk_bf(p1[2], p1[3]);
      int srcA = cl + 16*((2*gr) & 3);
      int srcB = srcA + 16;
      unsigned a0 = __shfl(u0, srcA, 64), b0 = __shfl(u1, srcA, 64);
      unsigned c0 = __shfl(u0, srcB, 64), d0 = __shfl(u1, srcB, 64);
      unsigned a2 = __shfl(u2, srcA, 64), b2 = __shfl(u3, srcA, 64);
      unsigned c2 = __shfl(u2, srcB, 64), d2 = __shfl(u3, srcB, 64);
      bool lo = gr < 2;
      union { unsigned u[4]; short8 v; } pbu;
      pbu.u[0] = lo ? a0 : a2;
      pbu.u[1] = lo ? b0 : b2;
      pbu.u[2] = lo ? c0 : c2;
      pbu.u[3] = lo ? d0 : d2;
      short8 pB = pbu.v;
      __builtin_amdgcn_s_setprio(1);
#pragma unroll
      for (int dt = 0; dt < 3; ++dt) {
        short8 aV = (dt < 2 || cl < 6)
            ? *(const short8*)&Vt[16*dt + cl][k0 + 8*gr] : z8;
        accO[dt] = __builtin_amdgcn_mfma_f32_16x16x32_bf16(aV, pB, accO[dt], 0, 0, 0);
      }
      __builtin_amdgcn_s_setprio(0);
    }
    { /* tail tile: keys 352..357 */
      int k0 = 352;
      int kr0 = k0 + cl; if (kr0 > 359) kr0 = 359;
      float4v s0a = (float4v){0,0,0,0};
      {
        short8 a00 = *(const short8*)&Ks[kr0][8*gr];
        s0a = __builtin_amdgcn_mfma_f32_16x16x32_bf16(a00, qB0, s0a, 0, 0, 0);
        short8 a01 = g0 ? *(const short8*)&Ks[kr0][32] : z8;
        s0a = __builtin_amdgcn_mfma_f32_16x16x32_bf16(a01, qB1, s0a, 0, 0, 0);
      }
      float p0[4];
#pragma unroll
      for (int r = 0; r < 4; ++r) {
        float xv = (4*gr + r < 6) ? s0a[r]*C2_ : -1e30f;
        p0[r] = __builtin_exp2f(fminf(xv, 80.f));
      }
      sum_ += (p0[0] + p0[1]) + (p0[2] + p0[3]);
      unsigned u0 = pk_bf(p0[0], p0[1]);
      unsigned u1 = pk_bf(p0[2], p0[3]);
      int srcA = cl + 16*((2*gr) & 3);
      int srcB = srcA + 16;
      unsigned a0 = __shfl(u0, srcA, 64), b0 = __shfl(u1, srcA, 64);
      unsigned c0 = __shfl(u0, srcB, 64), d0 = __shfl(u1, srcB, 64);
      bool lo = gr < 2;
      union { unsigned u[4]; short8 v; } pbu;
      pbu.u[0] = lo ? a0 : 0u;
      pbu.u[1] = lo ? b0 : 0u;
      pbu.u[2] = lo ? c0 : 0u;
      pbu.u[3] = lo ? d0 : 0u;
      short8 pB = pbu.v;
#pragma unroll
      for (int dt = 0; dt < 3; ++dt) {
        short8 aV = (dt < 2 || cl < 6)
            ? *(const short8*)&Vt[16*dt + cl][k0 + 8*gr] : z8;
        accO[dt] = __builtin_amdgcn_mfma_f32_16x16x32_bf16(aV, pB, accO[dt], 0, 0, 0);
      }
    }
    sum_ += __shfl_xor(sum_, 16, 64);
    sum_ += __shfl_xor(sum_, 32, 64);
    int qi = 16*qt + cl;
    if (qi < N_) {
      float inv = 1.f / sum_;
      bf* ap = a + (base + qi)*D_ + h*HD_;
#pragma unroll
      for (int dt = 0; dt < 2; ++dt) {
        *(unsigned*)(ap + 16*dt + 4*gr)     = pk_bf(accO[dt][0]*inv, accO[dt][1]*inv);
        *(unsigned*)(ap + 16*dt + 4*gr + 2) = pk_bf(accO[dt][2]*inv, accO[dt][3]*inv);
      }
      if (gr == 0) {
        *(unsigned*)(ap + 32) = pk_bf(accO[2][0]*inv, accO[2][1]*inv);
        *(unsigned*)(ap + 34) = pk_bf(accO[2][2]*inv, accO[2][3]*inv);
      } else if (gr == 1) {
        *(unsigned*)(ap + 36) = pk_bf(accO[2][0]*inv, accO[2][1]*inv);
      }
    }
  }
}

/* ------------------------------------------------------------------ */
__global__ __launch_bounds__(256) void k_evtpool(
    const float* __restrict__ marker, const void* __restrict__ doy_mask,
    const float* __restrict__ evt_h, float* __restrict__ evtp) {
  __shared__ int hasF32, hasBig;
  if (threadIdx.x == 0) { hasF32 = 0; hasBig = 0; }
  __syncthreads();
  const unsigned* mw = (const unsigned*)doy_mask;
  for (int w = threadIdx.x; w < 732; w += 256) {
    unsigned u = mw[w];
    if (u == 0x3F800000u) hasF32 = 1;
    else if (u > 1u) hasBig = 1;
  }
  __syncthreads();
  int fmt = hasF32 ? 2 : (hasBig ? 1 : 0);
  int b = blockIdx.x;
  float m3 = marker[((b*L_ + (L_-1))*N_ + 0)*4 + 3];
  int doy = (int)(m3 * 365.f); doy = doy < 0 ? 0 : (doy > 365 ? 365 : doy);
  int j = threadIdx.x;
  float mx = -1e30f;
  for (int kx = 0; kx < 8; ++kx) {
    bool mk;
    if (fmt == 2)      mk = ((const float*)doy_mask)[doy*8 + kx] != 0.f;
    else if (fmt == 1) mk = ((const unsigned char*)doy_mask)[doy*8 + kx] != 0;
    else               mk = ((const int*)doy_mask)[doy*8 + kx] != 0;
    if (mk) mx = fmaxf(mx, evt_h[(b*8 + kx)*256 + j]);
  }
  evtp[b*256 + j] = mx;
}

/* ------------------------------------------------------------------ */
__global__ __launch_bounds__(192) void k_final3(
    const bf* __restrict__ x, const float* __restrict__ wcomb,
    const float* __restrict__ wevtsum, const float* __restrict__ evtp,
    const float* __restrict__ b_mm, const float* __restrict__ b_ts,
    float* __restrict__ out) {
  int id = blockIdx.x; int b = id / N_; int n = id % N_;
  __shared__ float xs[1824];
  __shared__ float part[16][12];
  int tid = threadIdx.x;
  for (int e = tid; e < 912; e += 192) {
    int l = e / 76, du = e % 76;
    unsigned u = *(const unsigned*)((const ushort*)x +
        (((long)(b*L_ + l) * N_ + n) * 152 + 2*du));
    xs[l*152 + 2*du]     = lo_bf(u);
    xs[l*152 + 2*du + 1] = hi_bf(u);
  }
  __syncthreads();
  int g2 = tid / 12, p = tid % 12;
  float acc = 0.f;
  for (int e = g2; e < 1824; e += 16)
    acc += xs[e] * wcomb[e*12 + p];
  part[g2][p] = acc;
  __syncthreads();
  if (tid < 12) {
    float s = b_mm[tid] + b_ts[tid];
    for (int e = 0; e < 256; ++e) s += evtp[b*256 + e] * wevtsum[e*12 + tid];
    for (int gg = 0; gg < 16; ++gg) s += part[gg][tid];
    out[(b*12 + tid) * N_ + n] = s;
  }
}

/* ------------------------------------------------------------------ */
extern "C" void kernel_launch(void* const* d_in, const int* in_sizes, int n_in,
                              void* d_out, int out_size, void* d_ws, size_t ws_size,
                              hipStream_t stream) {
  static const int expect[32] = {
    68736, 274944, 72, 24, 3456, 168, 343680,
    138624, 912, 138624, 912, 138624, 912, 138624, 912,
    233472, 1536, 233472, 912,
    912, 912, 912, 912,
    4195328, 262144, 256,
    58752, 12, 21888, 12,
    2928, 2928 };
  int nb = (out_size + 255)/256;
  if (n_in != 32) {
    k_beacon<<<nb, 256, 0, stream>>>((float*)d_out, out_size, 998.f);
    return;
  }
  for (int i = 0; i < 32; ++i) {
    if (in_sizes[i] != expect[i]) {
      k_beacon<<<nb, 256, 0, stream>>>((float*)d_out, out_size, 1000.f + i);
      return;
    }
  }
  if (out_size != 68736) {
    k_beacon<<<nb, 256, 0, stream>>>((float*)d_out, out_size, 997.f);
    return;
  }

  const float* var_x  = (const float*)d_in[0];
  const float* marker = (const float*)d_in[1];
  const float* W_in   = (const float*)d_in[2];
  const float* b_in   = (const float*)d_in[3];
  const float* tod    = (const float*)d_in[4];
  const float* dow    = (const float*)d_in[5];
  const float* adap   = (const float*)d_in[6];
  const float* Wq = (const float*)d_in[7];  const float* bq = (const float*)d_in[8];
  const float* Wk = (const float*)d_in[9];  const float* bk = (const float*)d_in[10];
  const float* Wv = (const float*)d_in[11]; const float* bv = (const float*)d_in[12];
  const float* Wo = (const float*)d_in[13]; const float* bo = (const float*)d_in[14];
  const float* W1 = (const float*)d_in[15]; const float* b1 = (const float*)d_in[16];
  const float* W2 = (const float*)d_in[17]; const float* b2 = (const float*)d_in[18];
  const float* g1 = (const float*)d_in[19]; const float* be1 = (const float*)d_in[20];
  const float* g2 = (const float*)d_in[21]; const float* be2 = (const float*)d_in[22];
  const float* emb   = (const float*)d_in[23];
  const float* W_evt = (const float*)d_in[24]; const float* b_evt = (const float*)d_in[25];
  const float* W_mm  = (const float*)d_in[26]; const float* b_mm  = (const float*)d_in[27];
  const float* W_ts  = (const float*)d_in[28]; const float* b_ts  = (const float*)d_in[29];
  const int* doyi = (const int*)d_in[30];
  const void* doym = d_in[31];

  const long TD = (long)TOK_ * D_;
  size_t need = (size_t)TD * 2 * 5
              + (size_t)(32768 + 4096 + 3072 + 21888) * 4
              + 2764800
              + 4096;
  if (ws_size < need) {
    k_beacon<<<nb, 256, 0, stream>>>((float*)d_out, out_size, (float)(ws_size >> 20));
    return;
  }

  bf* x = (bf*)d_ws;
  bf* q = x + TD;
  bf* k = q + TD;
  bf* v = k + TD;
  bf* a = v + TD;
  float* evt_h   = (float*)(a + TD);
  float* evtp    = evt_h + 32768;
  float* wevtsum = evtp + 4096;
  float* wcomb   = wevtsum + 3072;
  ushort* wprep  = (ushort*)(wcomb + 21888);

  k_prep<<<PREP_B, 256, 0, stream>>>(
      Wq, Wk, Wv, Wo, W1, W2, (unsigned*)wprep,
      var_x, marker, W_in, b_in, tod, dow, adap, x,
      doyi, emb, W_evt, b_evt, evt_h,
      W_mm, W_ts, wcomb, wevtsum);
  k_evtpool<<<16, 256, 0, stream>>>(marker, doym, evt_h, evtp);
  for (int i = 0; i < 6; ++i) {
    const ushort* pl = wprep + (size_t)i * 230400;
    /* fused QKV projection (64-tok blocks) */
    k_gemm7<152,152,3,64,1,false,false><<<TOK_/64, 512, 0, stream>>>(
        x, pl, bq + i*152, bk + i*152, bv + i*152,
        nullptr, nullptr, nullptr, q, k, v);
    if (i < 3)
      k_attn_t2<<<B_*N_, 256, 0, stream>>>(
          (const ushort*)q, (const ushort*)k, (const ushort*)v, a);
    else
      k_attn_s6<<<B_*L_*4, 512, 0, stream>>>(
          (const ushort*)q, (const ushort*)k, (const ushort*)v, a);
    /* fused Wo+LN1+FFN+LN2: x = LN2( FF(LN1(a@Wo + bo + x)) + h ) */
    k_layer3<<<TOK_/64, 512, 0, stream>>>(
        a, x, pl + 96000, pl + 128000, pl + 179200,
        bo + i*152, b1 + i*256, b2 + i*152,
        g1 + i*152, be1 + i*152, g2 + i*152, be2 + i*152, x);
  }
  k_final3<<<B_*N_, 192, 0, stream>>>(x, wcomb, wevtsum, evtp, b_mm, b_ts,
                                      (float*)d_out);
}